// Round 3
// baseline (746.001 us; speedup 1.0000x reference)
//
#include <hip/hip_runtime.h>
#include <math.h>
#include <stddef.h>

#define NB 16
#define ND 64
#define NN 4096
#define NCD 8
#define NITER 4
#define ATT_EPS 1e-8f
#define LNEPS 1e-5f
#define QSCALE 0.125f

// ---- workspace layout (float offsets) ----
static constexpr size_t OFF_FCN  = 0;
static constexpr size_t SZ_FCN   = (size_t)NB*NN*NCD;          // 524288
static constexpr size_t OFF_KF   = OFF_FCN + SZ_FCN;
static constexpr size_t SZ_MAT   = (size_t)NB*NN*ND;           // 4194304
static constexpr size_t OFF_VF   = OFF_KF + SZ_MAT;
static constexpr size_t OFF_XKBG = OFF_VF + SZ_MAT;
static constexpr size_t OFF_XVBG = OFF_XKBG + SZ_MAT;
static constexpr size_t OFF_ACC  = OFF_XVBG + SZ_MAT;
static constexpr size_t SZ_ACC   = (size_t)NB*384;
static constexpr size_t OFF_SFG  = OFF_ACC + SZ_ACC;           // B*4*64
static constexpr size_t OFF_SBG  = OFF_SFG + (size_t)NB*256;   // B*64
static constexpr size_t OFF_POS  = OFF_SBG + (size_t)NB*64;    // B*4*2
static constexpr size_t OFF_QW   = OFF_POS + (size_t)NB*8;     // B*4*64
static constexpr size_t OFF_QB   = OFF_QW + (size_t)NB*256;    // B*4
static constexpr size_t OFF_QWBG = OFF_QB + (size_t)NB*4;      // B*64
static constexpr size_t OFF_QBBG = OFF_QWBG + (size_t)NB*64;   // B

// per-b accumulator layout (stride 384)
#define A_S 0
#define A_P 8
#define A_T 16
#define A_C 24
#define A_Y 64
#define A_YBG 320

// ---- helpers ----
__device__ __forceinline__ float g16sum(float x){
  x += __shfl_xor(x, 1);
  x += __shfl_xor(x, 2);
  x += __shfl_xor(x, 4);
  x += __shfl_xor(x, 8);
  return x;
}
__device__ __forceinline__ float wavesum(float x){
  x += __shfl_xor(x, 1);  x += __shfl_xor(x, 2);
  x += __shfl_xor(x, 4);  x += __shfl_xor(x, 8);
  x += __shfl_xor(x, 16); x += __shfl_xor(x, 32);
  return x;
}
__device__ __forceinline__ float4 f4fma(float a, float4 w, float4 c){
  c.x = fmaf(a, w.x, c.x); c.y = fmaf(a, w.y, c.y);
  c.z = fmaf(a, w.z, c.z); c.w = fmaf(a, w.w, c.w);
  return c;
}
// 64-dim LayerNorm over a 16-lane group (4 elems/lane), returns g*xhat+b
__device__ __forceinline__ float4 ln16v(float4 x, float4 g, float4 bb){
  float m = g16sum(x.x + x.y + x.z + x.w) * (1.0f/64.0f);
  float4 c = make_float4(x.x - m, x.y - m, x.z - m, x.w - m);
  float var = g16sum(c.x*c.x + c.y*c.y + c.z*c.z + c.w*c.w) * (1.0f/64.0f);
  float rs = rsqrtf(var + LNEPS);
  return make_float4(c.x*rs*g.x + bb.x, c.y*rs*g.y + bb.y,
                     c.z*rs*g.z + bb.z, c.w*rs*g.w + bb.w);
}
#define XRED(x) do { x += __shfl_xor(x, 16); x += __shfl_xor(x, 32); } while (0)

// ---- kernel: LN(feat_color) -> fcn ----
__global__ __launch_bounds__(256) void k_fcln(const float* __restrict__ fc,
                                              const float* __restrict__ g,
                                              const float* __restrict__ bb,
                                              float* __restrict__ ws){
  const int t = blockIdx.x*256 + threadIdx.x;
  if (t >= NB*NN) return;
  const float4* p = (const float4*)(fc + (size_t)t*8);
  float4 a = p[0], b4 = p[1];
  float v[8] = {a.x,a.y,a.z,a.w,b4.x,b4.y,b4.z,b4.w};
  float m = 0;
  #pragma unroll
  for (int i = 0; i < 8; ++i) m += v[i];
  m *= 0.125f;
  float var = 0;
  #pragma unroll
  for (int i = 0; i < 8; ++i){ float d = v[i]-m; var += d*d; }
  var *= 0.125f;
  float rs = rsqrtf(var + LNEPS);
  float o[8];
  #pragma unroll
  for (int i = 0; i < 8; ++i) o[i] = (v[i]-m)*rs*g[i] + bb[i];
  float4* q = (float4*)(ws + OFF_FCN + (size_t)t*8);
  q[0] = make_float4(o[0],o[1],o[2],o[3]);
  q[1] = make_float4(o[4],o[5],o[6],o[7]);
}

// ---- kernel: precompute kf, vf, xkbg, xvbg ----
__global__ __launch_bounds__(512) void k_pre(
    const float* __restrict__ feat,
    const float* __restrict__ w_kfg, const float* __restrict__ w_vfg,
    const float* __restrict__ w_kbg, const float* __restrict__ w_vbg,
    const float* __restrict__ w_grid, const float* __restrict__ b_grid,
    const float* __restrict__ ln_feat_g, const float* __restrict__ ln_feat_b,
    const float* __restrict__ ln_bg_g, const float* __restrict__ ln_bg_b,
    float* __restrict__ ws)
{
  __shared__ float4 Wt[4][64][16];   // [mat][e][d/4] : Wt[m][e][s].j = W_m[4s+j][e]
  const int tid = threadIdx.x;
  for (int idx = tid; idx < 4096; idx += 512){
    const int d = idx >> 6, e = idx & 63;
    ((float*)&Wt[0][e][0])[d] = w_kfg[idx];
    ((float*)&Wt[1][e][0])[d] = w_vfg[idx];
    ((float*)&Wt[2][e][0])[d] = w_kbg[idx];
    ((float*)&Wt[3][e][0])[d] = w_vbg[idx];
  }
  const int G = tid >> 4, s = tid & 15, e0 = 4*s;
  const int lanebase = (tid & 63) & ~15;
  const float4 lfg4 = *(const float4*)(ln_feat_g + e0);
  const float4 lfb4 = *(const float4*)(ln_feat_b + e0);
  const float4 lbg4 = *(const float4*)(ln_bg_g + e0);
  const float4 lbb4 = *(const float4*)(ln_bg_b + e0);
  const float4 bgr4 = *(const float4*)(b_grid + e0);
  float4 wgx4, wgy4;
  {
    float4 w0 = *(const float4*)(w_grid + (e0+0)*4);
    float4 w1 = *(const float4*)(w_grid + (e0+1)*4);
    float4 w2 = *(const float4*)(w_grid + (e0+2)*4);
    float4 w3 = *(const float4*)(w_grid + (e0+3)*4);
    wgx4 = make_float4(w0.x-w0.z, w1.x-w1.z, w2.x-w2.z, w3.x-w3.z);
    wgy4 = make_float4(w0.y-w0.w, w1.y-w1.w, w2.y-w2.w, w3.y-w3.w);
  }
  __syncthreads();
  float* kf   = ws + OFF_KF;
  float* vf   = ws + OFF_VF;
  float* xkbg = ws + OFF_XKBG;
  float* xvbg = ws + OFF_XVBG;

  for (int i = 0; i < 4; ++i){
    const int t = blockIdx.x*128 + G*4 + i;   // token in [0, B*N)
    const int n = t & (NN-1);
    const size_t fb = (size_t)t*64 + e0;
    const float4 f4 = *(const float4*)(feat + fb);
    const float4 fn = ln16v(f4, lfg4, lfb4);
    float4 acc0 = make_float4(0,0,0,0), acc1 = acc0, acc2 = acc0, acc3 = acc0;
    #pragma unroll
    for (int ee = 0; ee < 16; ++ee){
      const int src = lanebase + ee;
      const float f0 = __shfl(fn.x, src);
      const float f1 = __shfl(fn.y, src);
      const float f2 = __shfl(fn.z, src);
      const float f3 = __shfl(fn.w, src);
      acc0 = f4fma(f0, Wt[0][4*ee+0][s], acc0);
      acc0 = f4fma(f1, Wt[0][4*ee+1][s], acc0);
      acc0 = f4fma(f2, Wt[0][4*ee+2][s], acc0);
      acc0 = f4fma(f3, Wt[0][4*ee+3][s], acc0);
      acc1 = f4fma(f0, Wt[1][4*ee+0][s], acc1);
      acc1 = f4fma(f1, Wt[1][4*ee+1][s], acc1);
      acc1 = f4fma(f2, Wt[1][4*ee+2][s], acc1);
      acc1 = f4fma(f3, Wt[1][4*ee+3][s], acc1);
      acc2 = f4fma(f0, Wt[2][4*ee+0][s], acc2);
      acc2 = f4fma(f1, Wt[2][4*ee+1][s], acc2);
      acc2 = f4fma(f2, Wt[2][4*ee+2][s], acc2);
      acc2 = f4fma(f3, Wt[2][4*ee+3][s], acc2);
      acc3 = f4fma(f0, Wt[3][4*ee+0][s], acc3);
      acc3 = f4fma(f1, Wt[3][4*ee+1][s], acc3);
      acc3 = f4fma(f2, Wt[3][4*ee+2][s], acc3);
      acc3 = f4fma(f3, Wt[3][4*ee+3][s], acc3);
    }
    *(float4*)(kf + fb) = acc0;
    *(float4*)(vf + fb) = acc1;
    // bg branch: + ge_bg, then LN with ln_bg
    const float gx = -1.0f + (2.0f/63.0f)*(float)(n & 63);
    const float gy = -1.0f + (2.0f/63.0f)*(float)(n >> 6);
    const float4 ge = make_float4(
        fmaf(gx, wgx4.x, fmaf(gy, wgy4.x, bgr4.x)),
        fmaf(gx, wgx4.y, fmaf(gy, wgy4.y, bgr4.y)),
        fmaf(gx, wgx4.z, fmaf(gy, wgy4.z, bgr4.z)),
        fmaf(gx, wgx4.w, fmaf(gy, wgy4.w, bgr4.w)));
    float4 xk = make_float4(acc2.x+ge.x, acc2.y+ge.y, acc2.z+ge.z, acc2.w+ge.w);
    *(float4*)(xkbg + fb) = ln16v(xk, lbg4, lbb4);
    float4 xv = make_float4(acc3.x+ge.x, acc3.y+ge.y, acc3.z+ge.z, acc3.w+ge.w);
    *(float4*)(xvbg + fb) = ln16v(xv, lbg4, lbb4);
  }
}

// ---- kernel: init slot state ----
__global__ void k_init(const float* __restrict__ sfg0, const float* __restrict__ sbg0,
                       const float* __restrict__ pos0, float* __restrict__ ws){
  const int t = blockIdx.x*256 + threadIdx.x;
  if (t < NB*256) ws[OFF_SFG + t] = sfg0[t & 255];
  if (t < NB*64)  ws[OFF_SBG + t] = sbg0[t & 63];
  if (t < NB*8)   ws[OFF_POS + t] = pos0[t & 7];
}

// ---- kernel: per-iter q / qW precompute + zero accumulators ----
__global__ __launch_bounds__(64) void k_prep(
    const float* __restrict__ ln_q_g, const float* __restrict__ ln_q_b,
    const float* __restrict__ w_q,
    const float* __restrict__ ln_qbg_g, const float* __restrict__ ln_qbg_b,
    const float* __restrict__ w_qbg,
    const float* __restrict__ w_mlp_fg, const float* __restrict__ b_mlp_fg,
    const float* __restrict__ w_mlp_bg, const float* __restrict__ b_mlp_bg,
    float* __restrict__ ws)
{
  const int b = blockIdx.x, d = threadIdx.x;
  float* acc = ws + OFF_ACC + (size_t)b*384;
  for (int i = d; i < 384; i += 64) acc[i] = 0.0f;
  __shared__ float qin[64], qv[64];
  for (int k = 0; k < 4; ++k){
    const float sv = ws[OFF_SFG + b*256 + k*64 + d];
    const float m = wavesum(sv)*(1.0f/64.0f);
    const float c = sv - m;
    const float var = wavesum(c*c)*(1.0f/64.0f);
    const float rs = rsqrtf(var + LNEPS);
    qin[d] = c*rs*ln_q_g[d] + ln_q_b[d];
    __syncthreads();
    float q = 0;
    for (int e = 0; e < 64; ++e) q = fmaf(qin[e], w_q[d*64+e], q);
    qv[d] = q;
    __syncthreads();
    float qw = 0;
    for (int e = 0; e < 64; ++e) qw = fmaf(qv[e], w_mlp_fg[e*64+d], qw);
    ws[OFF_QW + b*256 + k*64 + d] = qw;
    const float qbv = wavesum(q * b_mlp_fg[d]);
    if (d == 0) ws[OFF_QB + b*4 + k] = qbv;
    __syncthreads();
  }
  {
    const float sv = ws[OFF_SBG + b*64 + d];
    const float m = wavesum(sv)*(1.0f/64.0f);
    const float c = sv - m;
    const float var = wavesum(c*c)*(1.0f/64.0f);
    const float rs = rsqrtf(var + LNEPS);
    qin[d] = c*rs*ln_qbg_g[d] + ln_qbg_b[d];
    __syncthreads();
    float q = 0;
    for (int e = 0; e < 64; ++e) q = fmaf(qin[e], w_qbg[d*64+e], q);
    qv[d] = q;
    __syncthreads();
    float qw = 0;
    for (int e = 0; e < 64; ++e) qw = fmaf(qv[e], w_mlp_bg[e*64+d], qw);
    ws[OFF_QWBG + b*64 + d] = qw;
    const float qbv = wavesum(q * b_mlp_bg[d]);
    if (d == 0) ws[OFF_QBBG + b] = qbv;
  }
}

// ---- main fused attention pass (per iteration) ----
template<int LAST>
__global__ __launch_bounds__(256) void k_main(
    const float* __restrict__ w_grid, const float* __restrict__ b_grid,
    const float* __restrict__ ln_fg_g, const float* __restrict__ ln_fg_b,
    const float* __restrict__ w_pos, float* __restrict__ ws)
{
  __shared__ float red[384];
  const int tid = threadIdx.x;
  const int b = blockIdx.y;
  for (int i = tid; i < 384; i += 256) red[i] = 0.0f;
  __syncthreads();

  const int G = tid >> 4;
  const int s = tid & 15;
  const int e0 = 4*s;

  float4 qw4[4];
  #pragma unroll
  for (int k = 0; k < 4; ++k)
    qw4[k] = *(const float4*)(ws + OFF_QW + (size_t)b*256 + k*64 + e0);
  const float4 qwbg4 = *(const float4*)(ws + OFF_QWBG + (size_t)b*64 + e0);
  float qb[4];
  #pragma unroll
  for (int k = 0; k < 4; ++k) qb[k] = ws[OFF_QB + b*4 + k];
  const float qbbg = ws[OFF_QBBG + b];
  float poskx[4], posky[4];
  #pragma unroll
  for (int k = 0; k < 4; ++k){
    poskx[k] = ws[OFF_POS + b*8 + k*2 + 0];
    posky[k] = ws[OFF_POS + b*8 + k*2 + 1];
  }
  float4 wgx4, wgy4;
  {
    float4 w0 = *(const float4*)(w_grid + (e0+0)*4);
    float4 w1 = *(const float4*)(w_grid + (e0+1)*4);
    float4 w2 = *(const float4*)(w_grid + (e0+2)*4);
    float4 w3 = *(const float4*)(w_grid + (e0+3)*4);
    wgx4 = make_float4(w0.x-w0.z, w1.x-w1.z, w2.x-w2.z, w3.x-w3.z);
    wgy4 = make_float4(w0.y-w0.w, w1.y-w1.w, w2.y-w2.w, w3.y-w3.w);
  }
  const float4 bgr4 = *(const float4*)(b_grid + e0);
  const float4 lng4 = *(const float4*)(ln_fg_g + e0);
  const float4 lnb4 = *(const float4*)(ln_fg_b + e0);

  const float* kf   = ws + OFF_KF;
  const float* vf   = ws + OFF_VF;
  const float* xkbg = ws + OFF_XKBG;
  const float* xvbg = ws + OFF_XVBG;
  const float* fcn  = ws + OFF_FCN;

  float accY[4][4] = {};
  float accYbg[4] = {};
  float accS[5] = {};
  float accP[4][2] = {};
  float accT[4][2] = {};
  float accC[5] = {};

  const int nbase = blockIdx.x*64 + G*4;
  for (int i = 0; i < 4; ++i){
    const int n = nbase + i;
    const size_t rbase = (((size_t)b << 12) + (size_t)n)*64 + e0;
    const float4 kf4  = *(const float4*)(kf + rbase);
    const float4 vf4  = *(const float4*)(vf + rbase);
    const float4 xkb4 = *(const float4*)(xkbg + rbase);
    const float4 xvb4 = *(const float4*)(xvbg + rbase);
    const float gx = -1.0f + (2.0f/63.0f)*(float)(n & 63);
    const float gy = -1.0f + (2.0f/63.0f)*(float)(n >> 6);
    float fcv = 0.0f, wpx = 0.0f, wpy = 0.0f;
    if (LAST){
      fcv = (s < 8) ? fcn[(((size_t)b << 12) + (size_t)n)*8 + s] : 0.0f;
    } else {
      wpx = w_pos[n]; wpy = w_pos[NN + n];
    }

    float a0 = g16sum(xkb4.x*qwbg4.x + xkb4.y*qwbg4.y + xkb4.z*qwbg4.z + xkb4.w*qwbg4.w);
    a0 = QSCALE*(a0 + qbbg);

    float a[4]; float lnv[4][4];
    #pragma unroll
    for (int k = 0; k < 4; ++k){
      const float rx = gx - poskx[k];
      const float ry = gy - posky[k];
      const float4 ge = make_float4(
          fmaf(rx, wgx4.x, fmaf(ry, wgy4.x, bgr4.x)),
          fmaf(rx, wgx4.y, fmaf(ry, wgy4.y, bgr4.y)),
          fmaf(rx, wgx4.z, fmaf(ry, wgy4.z, bgr4.z)),
          fmaf(rx, wgx4.w, fmaf(ry, wgy4.w, bgr4.w)));
      const float4 xk = make_float4(kf4.x+ge.x, kf4.y+ge.y, kf4.z+ge.z, kf4.w+ge.w);
      const float4 nk = ln16v(xk, lng4, lnb4);
      const float ak = g16sum(nk.x*qw4[k].x + nk.y*qw4[k].y + nk.z*qw4[k].z + nk.w*qw4[k].w);
      a[k] = QSCALE*(ak + qb[k]);
      const float4 xv = make_float4(vf4.x+ge.x, vf4.y+ge.y, vf4.z+ge.z, vf4.w+ge.w);
      const float4 nv = ln16v(xv, lng4, lnb4);
      lnv[k][0]=nv.x; lnv[k][1]=nv.y; lnv[k][2]=nv.z; lnv[k][3]=nv.w;
    }
    const float mx = fmaxf(fmaxf(fmaxf(a[0],a[1]), fmaxf(a[2],a[3])), a0);
    float p0 = __expf(a0 - mx);
    float pk[4];
    float sum = p0;
    #pragma unroll
    for (int k = 0; k < 4; ++k){ pk[k] = __expf(a[k]-mx); sum += pk[k]; }
    const float inv = 1.0f/sum;
    p0 = fmaf(p0, inv, ATT_EPS);
    #pragma unroll
    for (int k = 0; k < 4; ++k) pk[k] = fmaf(pk[k], inv, ATT_EPS);

    accS[0] += p0;
    accYbg[0] = fmaf(p0, xvb4.x, accYbg[0]);
    accYbg[1] = fmaf(p0, xvb4.y, accYbg[1]);
    accYbg[2] = fmaf(p0, xvb4.z, accYbg[2]);
    accYbg[3] = fmaf(p0, xvb4.w, accYbg[3]);
    if (LAST) accC[0] = fmaf(p0, fcv, accC[0]);
    #pragma unroll
    for (int k = 0; k < 4; ++k){
      accS[k+1] += pk[k];
      accY[k][0] = fmaf(pk[k], lnv[k][0], accY[k][0]);
      accY[k][1] = fmaf(pk[k], lnv[k][1], accY[k][1]);
      accY[k][2] = fmaf(pk[k], lnv[k][2], accY[k][2]);
      accY[k][3] = fmaf(pk[k], lnv[k][3], accY[k][3]);
      if (LAST){
        accC[k+1] = fmaf(pk[k], fcv, accC[k+1]);
      } else {
        accP[k][0] = fmaf(pk[k], gx, accP[k][0]);
        accP[k][1] = fmaf(pk[k], gy, accP[k][1]);
        accT[k][0] = fmaf(pk[k], wpx, accT[k][0]);
        accT[k][1] = fmaf(pk[k], wpy, accT[k][1]);
      }
    }
  }

  // cross-group (within-wave) reduction
  #pragma unroll
  for (int k = 0; k < 4; ++k){
    #pragma unroll
    for (int j = 0; j < 4; ++j){ float x = accY[k][j]; XRED(x); accY[k][j] = x; }
  }
  #pragma unroll
  for (int j = 0; j < 4; ++j){ float x = accYbg[j]; XRED(x); accYbg[j] = x; }
  #pragma unroll
  for (int sl = 0; sl < 5; ++sl){ float x = accS[sl]; XRED(x); accS[sl] = x; }
  #pragma unroll
  for (int sl = 0; sl < 5; ++sl){ float x = accC[sl]; XRED(x); accC[sl] = x; }
  #pragma unroll
  for (int k = 0; k < 4; ++k){
    float x;
    x = accP[k][0]; XRED(x); accP[k][0] = x;
    x = accP[k][1]; XRED(x); accP[k][1] = x;
    x = accT[k][0]; XRED(x); accT[k][0] = x;
    x = accT[k][1]; XRED(x); accT[k][1] = x;
  }

  const bool g0 = ((tid >> 4) & 3) == 0;
  if (g0){
    #pragma unroll
    for (int k = 0; k < 4; ++k){
      atomicAdd(&red[A_Y + k*64 + e0 + 0], accY[k][0]);
      atomicAdd(&red[A_Y + k*64 + e0 + 1], accY[k][1]);
      atomicAdd(&red[A_Y + k*64 + e0 + 2], accY[k][2]);
      atomicAdd(&red[A_Y + k*64 + e0 + 3], accY[k][3]);
    }
    atomicAdd(&red[A_YBG + e0 + 0], accYbg[0]);
    atomicAdd(&red[A_YBG + e0 + 1], accYbg[1]);
    atomicAdd(&red[A_YBG + e0 + 2], accYbg[2]);
    atomicAdd(&red[A_YBG + e0 + 3], accYbg[3]);
    if (s == 0){
      #pragma unroll
      for (int sl = 0; sl < 5; ++sl) atomicAdd(&red[A_S + sl], accS[sl]);
      if (!LAST){
        #pragma unroll
        for (int k = 0; k < 4; ++k){
          atomicAdd(&red[A_P + k*2 + 0], accP[k][0]);
          atomicAdd(&red[A_P + k*2 + 1], accP[k][1]);
          atomicAdd(&red[A_T + k*2 + 0], accT[k][0]);
          atomicAdd(&red[A_T + k*2 + 1], accT[k][1]);
        }
      }
    }
    if (LAST && s < 8){
      #pragma unroll
      for (int sl = 0; sl < 5; ++sl) atomicAdd(&red[A_C + sl*8 + s], accC[sl]);
    }
  }
  __syncthreads();
  float* gacc = ws + OFF_ACC + (size_t)b*384;
  for (int i = tid; i < 384; i += 256){
    const float v = red[i];
    if (v != 0.0f) atomicAdd(&gacc[i], v);
  }
}

// ---- per-iter slot update: upd-MLP, GRU, residual LN-MLP, pos ----
__global__ __launch_bounds__(64) void k_update(
    const float* __restrict__ w_mlp_fg, const float* __restrict__ b_mlp_fg,
    const float* __restrict__ w_mlp_bg, const float* __restrict__ b_mlp_bg,
    const float* __restrict__ gfg_wih, const float* __restrict__ gfg_whh,
    const float* __restrict__ gfg_bih, const float* __restrict__ gfg_bhh,
    const float* __restrict__ gbg_wih, const float* __restrict__ gbg_whh,
    const float* __restrict__ gbg_bih, const float* __restrict__ gbg_bhh,
    const float* __restrict__ ln_rfg_g, const float* __restrict__ ln_rfg_b,
    const float* __restrict__ w_rfg, const float* __restrict__ b_rfg,
    const float* __restrict__ ln_rbg_g, const float* __restrict__ ln_rbg_b,
    const float* __restrict__ w_rbg, const float* __restrict__ b_rbg,
    const float* __restrict__ b_pos, float* __restrict__ ws)
{
  const int b = blockIdx.x, d = threadIdx.x;
  float* acc = ws + OFF_ACC + (size_t)b*384;
  __shared__ float xl[64], hl[64], rl[64];
  for (int k = 0; k < 4; ++k){
    const float invS = 1.0f/acc[A_S + 1 + k];
    xl[d] = acc[A_Y + k*64 + d]*invS;
    __syncthreads();
    float upd = b_mlp_fg[d];
    for (int e = 0; e < 64; ++e) upd = fmaf(xl[e], w_mlp_fg[d*64+e], upd);
    const float h = ws[OFF_SFG + b*256 + k*64 + d];
    __syncthreads();
    xl[d] = upd; hl[d] = h;
    __syncthreads();
    float gir = gfg_bih[d], giz = gfg_bih[64+d], gin = gfg_bih[128+d];
    float ghr = gfg_bhh[d], ghz = gfg_bhh[64+d], ghn = gfg_bhh[128+d];
    for (int e = 0; e < 64; ++e){
      const float x = xl[e], hh = hl[e];
      gir = fmaf(x, gfg_wih[d*64+e], gir);
      giz = fmaf(x, gfg_wih[(64+d)*64+e], giz);
      gin = fmaf(x, gfg_wih[(128+d)*64+e], gin);
      ghr = fmaf(hh, gfg_whh[d*64+e], ghr);
      ghz = fmaf(hh, gfg_whh[(64+d)*64+e], ghz);
      ghn = fmaf(hh, gfg_whh[(128+d)*64+e], ghn);
    }
    const float r = 1.0f/(1.0f + expf(-(gir+ghr)));
    const float z = 1.0f/(1.0f + expf(-(giz+ghz)));
    const float nn = tanhf(fmaf(r, ghn, gin));
    const float hnew = (1.0f - z)*nn + z*h;
    const float m = wavesum(hnew)*(1.0f/64.0f);
    const float c = hnew - m;
    const float var = wavesum(c*c)*(1.0f/64.0f);
    const float rs = rsqrtf(var + LNEPS);
    rl[d] = c*rs*ln_rfg_g[d] + ln_rfg_b[d];
    __syncthreads();
    float outv = hnew + b_rfg[d];
    for (int e = 0; e < 64; ++e) outv = fmaf(rl[e], w_rfg[d*64+e], outv);
    ws[OFF_SFG + b*256 + k*64 + d] = outv;
    if (d < 2){
      const float P = acc[A_P + k*2 + d]*invS;
      const float T = acc[A_T + k*2 + d]*invS;
      float pn = P + tanhf(T + b_pos[d])*0.2f;
      pn = fminf(1.0f, fmaxf(-1.0f, pn));
      ws[OFF_POS + b*8 + k*2 + d] = pn;
    }
    __syncthreads();
  }
  {
    const float invS = 1.0f/acc[A_S + 0];
    xl[d] = acc[A_YBG + d]*invS;
    __syncthreads();
    float upd = b_mlp_bg[d];
    for (int e = 0; e < 64; ++e) upd = fmaf(xl[e], w_mlp_bg[d*64+e], upd);
    const float h = ws[OFF_SBG + b*64 + d];
    __syncthreads();
    xl[d] = upd; hl[d] = h;
    __syncthreads();
    float gir = gbg_bih[d], giz = gbg_bih[64+d], gin = gbg_bih[128+d];
    float ghr = gbg_bhh[d], ghz = gbg_bhh[64+d], ghn = gbg_bhh[128+d];
    for (int e = 0; e < 64; ++e){
      const float x = xl[e], hh = hl[e];
      gir = fmaf(x, gbg_wih[d*64+e], gir);
      giz = fmaf(x, gbg_wih[(64+d)*64+e], giz);
      gin = fmaf(x, gbg_wih[(128+d)*64+e], gin);
      ghr = fmaf(hh, gbg_whh[d*64+e], ghr);
      ghz = fmaf(hh, gbg_whh[(64+d)*64+e], ghz);
      ghn = fmaf(hh, gbg_whh[(128+d)*64+e], ghn);
    }
    const float r = 1.0f/(1.0f + expf(-(gir+ghr)));
    const float z = 1.0f/(1.0f + expf(-(giz+ghz)));
    const float nn = tanhf(fmaf(r, ghn, gin));
    const float hnew = (1.0f - z)*nn + z*h;
    const float m = wavesum(hnew)*(1.0f/64.0f);
    const float c = hnew - m;
    const float var = wavesum(c*c)*(1.0f/64.0f);
    const float rs = rsqrtf(var + LNEPS);
    rl[d] = c*rs*ln_rbg_g[d] + ln_rbg_b[d];
    __syncthreads();
    float outv = hnew + b_rbg[d];
    for (int e = 0; e < 64; ++e) outv = fmaf(rl[e], w_rbg[d*64+e], outv);
    ws[OFF_SBG + b*64 + d] = outv;
  }
}

// ---- final output kernel ----
__global__ __launch_bounds__(64) void k_final(
    const float* __restrict__ w_mlp_fg, const float* __restrict__ b_mlp_fg,
    const float* __restrict__ w_mlp_bg, const float* __restrict__ b_mlp_bg,
    const float* __restrict__ ws, float* __restrict__ out)
{
  const int b = blockIdx.x, d = threadIdx.x;
  const float* acc = ws + OFF_ACC + (size_t)b*384;
  __shared__ float xl[64];
  {
    const float invS = 1.0f/acc[A_S];
    xl[d] = acc[A_YBG + d]*invS;
    __syncthreads();
    float o = b_mlp_bg[d];
    for (int e = 0; e < 64; ++e) o = fmaf(xl[e], w_mlp_bg[d*64+e], o);
    out[(b*5 + 0)*72 + d] = o;
    if (d < 8) out[(b*5 + 0)*72 + 64 + d] = acc[A_C + d]*invS;
    __syncthreads();
  }
  for (int k = 0; k < 4; ++k){
    const float invS = 1.0f/acc[A_S + 1 + k];
    xl[d] = acc[A_Y + k*64 + d]*invS;
    __syncthreads();
    float o = b_mlp_fg[d];
    for (int e = 0; e < 64; ++e) o = fmaf(xl[e], w_mlp_fg[d*64+e], o);
    out[(b*5 + 1 + k)*72 + d] = o;
    if (d < 8) out[(b*5 + 1 + k)*72 + 64 + d] = acc[A_C + (k+1)*8 + d]*invS;
    __syncthreads();
  }
}

extern "C" void kernel_launch(void* const* d_in, const int* in_sizes, int n_in,
                              void* d_out, int out_size, void* d_ws, size_t ws_size,
                              hipStream_t stream)
{
  const float* feat          = (const float*)d_in[0];
  const float* feat_color    = (const float*)d_in[1];
  const float* w_grid        = (const float*)d_in[2];
  const float* b_grid        = (const float*)d_in[3];
  const float* w_kfg         = (const float*)d_in[4];
  const float* w_vfg         = (const float*)d_in[5];
  const float* w_kbg         = (const float*)d_in[6];
  const float* w_vbg         = (const float*)d_in[7];
  const float* ln_fg_g       = (const float*)d_in[8];
  const float* ln_fg_b       = (const float*)d_in[9];
  const float* w_mlp_fg      = (const float*)d_in[10];
  const float* b_mlp_fg      = (const float*)d_in[11];
  const float* ln_bg_g       = (const float*)d_in[12];
  const float* ln_bg_b       = (const float*)d_in[13];
  const float* w_mlp_bg      = (const float*)d_in[14];
  const float* b_mlp_bg      = (const float*)d_in[15];
  const float* slots_init_fg = (const float*)d_in[16];
  const float* slots_init_bg = (const float*)d_in[17];
  const float* fg_position   = (const float*)d_in[18];
  const float* w_pos         = (const float*)d_in[19];
  const float* b_pos         = (const float*)d_in[20];
  const float* ln_q_g        = (const float*)d_in[21];
  const float* ln_q_b        = (const float*)d_in[22];
  const float* w_q           = (const float*)d_in[23];
  const float* ln_qbg_g      = (const float*)d_in[24];
  const float* ln_qbg_b      = (const float*)d_in[25];
  const float* w_qbg         = (const float*)d_in[26];
  const float* gfg_wih       = (const float*)d_in[27];
  const float* gfg_whh       = (const float*)d_in[28];
  const float* gfg_bih       = (const float*)d_in[29];
  const float* gfg_bhh       = (const float*)d_in[30];
  const float* gbg_wih       = (const float*)d_in[31];
  const float* gbg_whh       = (const float*)d_in[32];
  const float* gbg_bih       = (const float*)d_in[33];
  const float* gbg_bhh       = (const float*)d_in[34];
  const float* ln_rfg_g      = (const float*)d_in[35];
  const float* ln_rfg_b      = (const float*)d_in[36];
  const float* w_rfg         = (const float*)d_in[37];
  const float* b_rfg         = (const float*)d_in[38];
  const float* ln_rbg_g      = (const float*)d_in[39];
  const float* ln_rbg_b      = (const float*)d_in[40];
  const float* w_rbg         = (const float*)d_in[41];
  const float* b_rbg         = (const float*)d_in[42];
  const float* ln_feat_g     = (const float*)d_in[43];
  const float* ln_feat_b     = (const float*)d_in[44];
  const float* ln_fc_g       = (const float*)d_in[45];
  const float* ln_fc_b       = (const float*)d_in[46];
  float* ws  = (float*)d_ws;
  float* out = (float*)d_out;

  hipLaunchKernelGGL(k_fcln, dim3(256), dim3(256), 0, stream,
                     feat_color, ln_fc_g, ln_fc_b, ws);
  hipLaunchKernelGGL(k_pre, dim3(512), dim3(512), 0, stream,
                     feat, w_kfg, w_vfg, w_kbg, w_vbg, w_grid, b_grid,
                     ln_feat_g, ln_feat_b, ln_bg_g, ln_bg_b, ws);
  hipLaunchKernelGGL(k_init, dim3(16), dim3(256), 0, stream,
                     slots_init_fg, slots_init_bg, fg_position, ws);
  for (int it = 0; it < NITER; ++it){
    hipLaunchKernelGGL(k_prep, dim3(16), dim3(64), 0, stream,
                       ln_q_g, ln_q_b, w_q, ln_qbg_g, ln_qbg_b, w_qbg,
                       w_mlp_fg, b_mlp_fg, w_mlp_bg, b_mlp_bg, ws);
    if (it < NITER-1){
      hipLaunchKernelGGL((k_main<0>), dim3(64,16), dim3(256), 0, stream,
                         w_grid, b_grid, ln_fg_g, ln_fg_b, w_pos, ws);
      hipLaunchKernelGGL(k_update, dim3(16), dim3(64), 0, stream,
                         w_mlp_fg, b_mlp_fg, w_mlp_bg, b_mlp_bg,
                         gfg_wih, gfg_whh, gfg_bih, gfg_bhh,
                         gbg_wih, gbg_whh, gbg_bih, gbg_bhh,
                         ln_rfg_g, ln_rfg_b, w_rfg, b_rfg,
                         ln_rbg_g, ln_rbg_b, w_rbg, b_rbg,
                         b_pos, ws);
    } else {
      hipLaunchKernelGGL((k_main<1>), dim3(64,16), dim3(256), 0, stream,
                         w_grid, b_grid, ln_fg_g, ln_fg_b, w_pos, ws);
      hipLaunchKernelGGL(k_final, dim3(16), dim3(64), 0, stream,
                         w_mlp_fg, b_mlp_fg, w_mlp_bg, b_mlp_bg, ws, out);
    }
  }
}

// Round 4
// 372.611 us; speedup vs baseline: 2.0021x; 2.0021x over previous
//
#include <hip/hip_runtime.h>
#include <math.h>
#include <stddef.h>

#define NB 16
#define ND 64
#define NN 4096
#define NCD 8
#define NITER 4
#define ATT_EPS 1e-8f
#define LNEPS 1e-5f
#define QSCALE 0.125f

// ---- workspace layout (float offsets) ----
static constexpr size_t OFF_FCN  = 0;
static constexpr size_t SZ_FCN   = (size_t)NB*NN*NCD;          // 524288
static constexpr size_t OFF_KF   = OFF_FCN + SZ_FCN;
static constexpr size_t SZ_MAT   = (size_t)NB*NN*ND;           // 4194304
static constexpr size_t OFF_VF   = OFF_KF + SZ_MAT;
static constexpr size_t OFF_XKBG = OFF_VF + SZ_MAT;
static constexpr size_t OFF_XVBG = OFF_XKBG + SZ_MAT;
static constexpr size_t OFF_ACC  = OFF_XVBG + SZ_MAT;
static constexpr size_t SZ_ACC   = (size_t)NB*384;
static constexpr size_t OFF_SFG  = OFF_ACC + SZ_ACC;           // B*4*64
static constexpr size_t OFF_SBG  = OFF_SFG + (size_t)NB*256;   // B*64
static constexpr size_t OFF_POS  = OFF_SBG + (size_t)NB*64;    // B*4*2
static constexpr size_t OFF_QW   = OFF_POS + (size_t)NB*8;     // B*4*64
static constexpr size_t OFF_QB   = OFF_QW + (size_t)NB*256;    // B*4
static constexpr size_t OFF_QWBG = OFF_QB + (size_t)NB*4;      // B*64
static constexpr size_t OFF_QBBG = OFF_QWBG + (size_t)NB*64;   // B

// per-b accumulator layout (stride 384)
#define A_S 0
#define A_P 8
#define A_T 16
#define A_C 24
#define A_Y 64
#define A_YBG 320

// ---- helpers ----
__device__ __forceinline__ float g16sum(float x){
  x += __shfl_xor(x, 1);
  x += __shfl_xor(x, 2);
  x += __shfl_xor(x, 4);
  x += __shfl_xor(x, 8);
  return x;
}
__device__ __forceinline__ float wavesum(float x){
  x += __shfl_xor(x, 1);  x += __shfl_xor(x, 2);
  x += __shfl_xor(x, 4);  x += __shfl_xor(x, 8);
  x += __shfl_xor(x, 16); x += __shfl_xor(x, 32);
  return x;
}
__device__ __forceinline__ float4 f4fma(float a, float4 w, float4 c){
  c.x = fmaf(a, w.x, c.x); c.y = fmaf(a, w.y, c.y);
  c.z = fmaf(a, w.z, c.z); c.w = fmaf(a, w.w, c.w);
  return c;
}
// 64-dim LayerNorm over a 16-lane group (4 elems/lane), returns g*xhat+b
__device__ __forceinline__ float4 ln16v(float4 x, float4 g, float4 bb){
  float m = g16sum(x.x + x.y + x.z + x.w) * (1.0f/64.0f);
  float4 c = make_float4(x.x - m, x.y - m, x.z - m, x.w - m);
  float var = g16sum(c.x*c.x + c.y*c.y + c.z*c.z + c.w*c.w) * (1.0f/64.0f);
  float rs = rsqrtf(var + LNEPS);
  return make_float4(c.x*rs*g.x + bb.x, c.y*rs*g.y + bb.y,
                     c.z*rs*g.z + bb.z, c.w*rs*g.w + bb.w);
}
#define XRED(x) do { x += __shfl_xor(x, 16); x += __shfl_xor(x, 32); } while (0)

// ---- kernel: LN(feat_color) -> fcn ----
__global__ __launch_bounds__(256) void k_fcln(const float* __restrict__ fc,
                                              const float* __restrict__ g,
                                              const float* __restrict__ bb,
                                              float* __restrict__ ws){
  const int t = blockIdx.x*256 + threadIdx.x;
  if (t >= NB*NN) return;
  const float4* p = (const float4*)(fc + (size_t)t*8);
  float4 a = p[0], b4 = p[1];
  float v[8] = {a.x,a.y,a.z,a.w,b4.x,b4.y,b4.z,b4.w};
  float m = 0;
  #pragma unroll
  for (int i = 0; i < 8; ++i) m += v[i];
  m *= 0.125f;
  float var = 0;
  #pragma unroll
  for (int i = 0; i < 8; ++i){ float d = v[i]-m; var += d*d; }
  var *= 0.125f;
  float rs = rsqrtf(var + LNEPS);
  float o[8];
  #pragma unroll
  for (int i = 0; i < 8; ++i) o[i] = (v[i]-m)*rs*g[i] + bb[i];
  float4* q = (float4*)(ws + OFF_FCN + (size_t)t*8);
  q[0] = make_float4(o[0],o[1],o[2],o[3]);
  q[1] = make_float4(o[4],o[5],o[6],o[7]);
}

// ---- kernel: precompute kf, vf, xkbg, xvbg (register-blocked GEMM) ----
// grid = 1024 blocks x 256 threads. half = bid>>9 (0: kf/vf, 1: xkbg/xvbg).
// Block handles 128 tokens x 128 cols (2 matrices of 64).
// Thread (i = tid>>4, j = tid&15) owns tokens {u*16+i, u=0..7}, cols {4j..4j+3} of each matrix.
__global__ __launch_bounds__(256) void k_pre(
    const float* __restrict__ feat,
    const float* __restrict__ w_kfg, const float* __restrict__ w_vfg,
    const float* __restrict__ w_kbg, const float* __restrict__ w_vbg,
    const float* __restrict__ w_grid, const float* __restrict__ b_grid,
    const float* __restrict__ ln_feat_g, const float* __restrict__ ln_feat_b,
    const float* __restrict__ ln_bg_g, const float* __restrict__ ln_bg_b,
    float* __restrict__ ws)
{
  __shared__ float fl[128][64];      // LN'd feat tile [token][e]   32 KB
  __shared__ float wl[2][64][64];    // weights^T      [mat][e][d]  32 KB
  const int tid  = threadIdx.x;
  const int bid  = blockIdx.x;
  const int half = bid >> 9;         // 0 = fg pair, 1 = bg pair
  const int tb   = bid & 511;        // token-block
  const int i    = tid >> 4;         // 0..15 token-group
  const int j    = tid & 15;         // 0..15 col-group
  const float* wA = half ? w_kbg : w_kfg;
  const float* wB = half ? w_vbg : w_vfg;

  // stage weights transposed: wl[m][e][d] = W_m[d][e]
  #pragma unroll
  for (int it = 0; it < 8; ++it){
    const int f = it*256 + tid;       // float4 id, 0..2047
    const int m = f >> 10;
    const int r = f & 1023;
    const int d = r >> 4;
    const int s = r & 15;
    const float* src = m ? wB : wA;
    const float4 wv = *(const float4*)(src + d*64 + 4*s);
    wl[m][4*s+0][d] = wv.x;
    wl[m][4*s+1][d] = wv.y;
    wl[m][4*s+2][d] = wv.z;
    wl[m][4*s+3][d] = wv.w;
  }
  // stage feat tile with LN (16 lanes per token)
  {
    const float4 lfg4 = *(const float4*)(ln_feat_g + 4*j);
    const float4 lfb4 = *(const float4*)(ln_feat_b + 4*j);
    #pragma unroll
    for (int it = 0; it < 8; ++it){
      const int tok = it*16 + i;
      const size_t gb = ((size_t)tb*128 + tok)*64 + 4*j;
      const float4 f4 = *(const float4*)(feat + gb);
      const float4 fn = ln16v(f4, lfg4, lfb4);
      *(float4*)&fl[tok][4*j] = fn;
    }
  }
  __syncthreads();

  float4 acc0[8], acc1[8];
  #pragma unroll
  for (int u = 0; u < 8; ++u){
    acc0[u] = make_float4(0,0,0,0);
    acc1[u] = make_float4(0,0,0,0);
  }
  for (int e0 = 0; e0 < 64; e0 += 4){
    float4 a[8];
    #pragma unroll
    for (int u = 0; u < 8; ++u) a[u] = *(const float4*)&fl[u*16 + i][e0];
    #pragma unroll
    for (int l = 0; l < 4; ++l){
      const float4 b0 = *(const float4*)&wl[0][e0+l][4*j];
      const float4 b1 = *(const float4*)&wl[1][e0+l][4*j];
      #pragma unroll
      for (int u = 0; u < 8; ++u){
        const float av = l==0 ? a[u].x : l==1 ? a[u].y : l==2 ? a[u].z : a[u].w;
        acc0[u] = f4fma(av, b0, acc0[u]);
        acc1[u] = f4fma(av, b1, acc1[u]);
      }
    }
  }

  if (!half){
    float* kf = ws + OFF_KF;
    float* vf = ws + OFF_VF;
    #pragma unroll
    for (int u = 0; u < 8; ++u){
      const size_t gb = ((size_t)tb*128 + u*16 + i)*64 + 4*j;
      *(float4*)(kf + gb) = acc0[u];
      *(float4*)(vf + gb) = acc1[u];
    }
  } else {
    // ge_bg + LN(ln_bg) epilogue
    float4 wgx4, wgy4;
    {
      float4 w0 = *(const float4*)(w_grid + (4*j+0)*4);
      float4 w1 = *(const float4*)(w_grid + (4*j+1)*4);
      float4 w2 = *(const float4*)(w_grid + (4*j+2)*4);
      float4 w3 = *(const float4*)(w_grid + (4*j+3)*4);
      wgx4 = make_float4(w0.x-w0.z, w1.x-w1.z, w2.x-w2.z, w3.x-w3.z);
      wgy4 = make_float4(w0.y-w0.w, w1.y-w1.w, w2.y-w2.w, w3.y-w3.w);
    }
    const float4 bgr4 = *(const float4*)(b_grid + 4*j);
    const float4 lbg4 = *(const float4*)(ln_bg_g + 4*j);
    const float4 lbb4 = *(const float4*)(ln_bg_b + 4*j);
    float* xkbg = ws + OFF_XKBG;
    float* xvbg = ws + OFF_XVBG;
    #pragma unroll
    for (int u = 0; u < 8; ++u){
      const int tok = u*16 + i;
      const size_t t = (size_t)tb*128 + tok;
      const int n = (int)(t & (NN-1));
      const float gx = -1.0f + (2.0f/63.0f)*(float)(n & 63);
      const float gy = -1.0f + (2.0f/63.0f)*(float)(n >> 6);
      const float4 ge = make_float4(
          fmaf(gx, wgx4.x, fmaf(gy, wgy4.x, bgr4.x)),
          fmaf(gx, wgx4.y, fmaf(gy, wgy4.y, bgr4.y)),
          fmaf(gx, wgx4.z, fmaf(gy, wgy4.z, bgr4.z)),
          fmaf(gx, wgx4.w, fmaf(gy, wgy4.w, bgr4.w)));
      const size_t gb = t*64 + 4*j;
      float4 xk = make_float4(acc0[u].x+ge.x, acc0[u].y+ge.y, acc0[u].z+ge.z, acc0[u].w+ge.w);
      *(float4*)(xkbg + gb) = ln16v(xk, lbg4, lbb4);
      float4 xv = make_float4(acc1[u].x+ge.x, acc1[u].y+ge.y, acc1[u].z+ge.z, acc1[u].w+ge.w);
      *(float4*)(xvbg + gb) = ln16v(xv, lbg4, lbb4);
    }
  }
}

// ---- kernel: init slot state ----
__global__ void k_init(const float* __restrict__ sfg0, const float* __restrict__ sbg0,
                       const float* __restrict__ pos0, float* __restrict__ ws){
  const int t = blockIdx.x*256 + threadIdx.x;
  if (t < NB*256) ws[OFF_SFG + t] = sfg0[t & 255];
  if (t < NB*64)  ws[OFF_SBG + t] = sbg0[t & 63];
  if (t < NB*8)   ws[OFF_POS + t] = pos0[t & 7];
}

// ---- kernel: per-iter q / qW precompute + zero accumulators ----
__global__ __launch_bounds__(64) void k_prep(
    const float* __restrict__ ln_q_g, const float* __restrict__ ln_q_b,
    const float* __restrict__ w_q,
    const float* __restrict__ ln_qbg_g, const float* __restrict__ ln_qbg_b,
    const float* __restrict__ w_qbg,
    const float* __restrict__ w_mlp_fg, const float* __restrict__ b_mlp_fg,
    const float* __restrict__ w_mlp_bg, const float* __restrict__ b_mlp_bg,
    float* __restrict__ ws)
{
  const int b = blockIdx.x, d = threadIdx.x;
  float* acc = ws + OFF_ACC + (size_t)b*384;
  for (int i = d; i < 384; i += 64) acc[i] = 0.0f;
  __shared__ float qin[64], qv[64];
  for (int k = 0; k < 4; ++k){
    const float sv = ws[OFF_SFG + b*256 + k*64 + d];
    const float m = wavesum(sv)*(1.0f/64.0f);
    const float c = sv - m;
    const float var = wavesum(c*c)*(1.0f/64.0f);
    const float rs = rsqrtf(var + LNEPS);
    qin[d] = c*rs*ln_q_g[d] + ln_q_b[d];
    __syncthreads();
    float q = 0;
    for (int e = 0; e < 64; ++e) q = fmaf(qin[e], w_q[d*64+e], q);
    qv[d] = q;
    __syncthreads();
    float qw = 0;
    for (int e = 0; e < 64; ++e) qw = fmaf(qv[e], w_mlp_fg[e*64+d], qw);
    ws[OFF_QW + b*256 + k*64 + d] = qw;
    const float qbv = wavesum(q * b_mlp_fg[d]);
    if (d == 0) ws[OFF_QB + b*4 + k] = qbv;
    __syncthreads();
  }
  {
    const float sv = ws[OFF_SBG + b*64 + d];
    const float m = wavesum(sv)*(1.0f/64.0f);
    const float c = sv - m;
    const float var = wavesum(c*c)*(1.0f/64.0f);
    const float rs = rsqrtf(var + LNEPS);
    qin[d] = c*rs*ln_qbg_g[d] + ln_qbg_b[d];
    __syncthreads();
    float q = 0;
    for (int e = 0; e < 64; ++e) q = fmaf(qin[e], w_qbg[d*64+e], q);
    qv[d] = q;
    __syncthreads();
    float qw = 0;
    for (int e = 0; e < 64; ++e) qw = fmaf(qv[e], w_mlp_bg[e*64+d], qw);
    ws[OFF_QWBG + b*64 + d] = qw;
    const float qbv = wavesum(q * b_mlp_bg[d]);
    if (d == 0) ws[OFF_QBBG + b] = qbv;
  }
}

// ---- main fused attention pass (per iteration) ----
template<int LAST>
__global__ __launch_bounds__(256) void k_main(
    const float* __restrict__ w_grid, const float* __restrict__ b_grid,
    const float* __restrict__ ln_fg_g, const float* __restrict__ ln_fg_b,
    const float* __restrict__ w_pos, float* __restrict__ ws)
{
  __shared__ float red[384];
  const int tid = threadIdx.x;
  const int b = blockIdx.y;
  for (int i = tid; i < 384; i += 256) red[i] = 0.0f;
  __syncthreads();

  const int G = tid >> 4;
  const int s = tid & 15;
  const int e0 = 4*s;

  float4 qw4[4];
  #pragma unroll
  for (int k = 0; k < 4; ++k)
    qw4[k] = *(const float4*)(ws + OFF_QW + (size_t)b*256 + k*64 + e0);
  const float4 qwbg4 = *(const float4*)(ws + OFF_QWBG + (size_t)b*64 + e0);
  float qb[4];
  #pragma unroll
  for (int k = 0; k < 4; ++k) qb[k] = ws[OFF_QB + b*4 + k];
  const float qbbg = ws[OFF_QBBG + b];
  float poskx[4], posky[4];
  #pragma unroll
  for (int k = 0; k < 4; ++k){
    poskx[k] = ws[OFF_POS + b*8 + k*2 + 0];
    posky[k] = ws[OFF_POS + b*8 + k*2 + 1];
  }
  float4 wgx4, wgy4;
  {
    float4 w0 = *(const float4*)(w_grid + (e0+0)*4);
    float4 w1 = *(const float4*)(w_grid + (e0+1)*4);
    float4 w2 = *(const float4*)(w_grid + (e0+2)*4);
    float4 w3 = *(const float4*)(w_grid + (e0+3)*4);
    wgx4 = make_float4(w0.x-w0.z, w1.x-w1.z, w2.x-w2.z, w3.x-w3.z);
    wgy4 = make_float4(w0.y-w0.w, w1.y-w1.w, w2.y-w2.w, w3.y-w3.w);
  }
  const float4 bgr4 = *(const float4*)(b_grid + e0);
  const float4 lng4 = *(const float4*)(ln_fg_g + e0);
  const float4 lnb4 = *(const float4*)(ln_fg_b + e0);

  const float* kf   = ws + OFF_KF;
  const float* vf   = ws + OFF_VF;
  const float* xkbg = ws + OFF_XKBG;
  const float* xvbg = ws + OFF_XVBG;
  const float* fcn  = ws + OFF_FCN;

  float accY[4][4] = {};
  float accYbg[4] = {};
  float accS[5] = {};
  float accP[4][2] = {};
  float accT[4][2] = {};
  float accC[5] = {};

  const int nbase = blockIdx.x*64 + G*4;
  for (int i = 0; i < 4; ++i){
    const int n = nbase + i;
    const size_t rbase = (((size_t)b << 12) + (size_t)n)*64 + e0;
    const float4 kf4  = *(const float4*)(kf + rbase);
    const float4 vf4  = *(const float4*)(vf + rbase);
    const float4 xkb4 = *(const float4*)(xkbg + rbase);
    const float4 xvb4 = *(const float4*)(xvbg + rbase);
    const float gx = -1.0f + (2.0f/63.0f)*(float)(n & 63);
    const float gy = -1.0f + (2.0f/63.0f)*(float)(n >> 6);
    float fcv = 0.0f, wpx = 0.0f, wpy = 0.0f;
    if (LAST){
      fcv = (s < 8) ? fcn[(((size_t)b << 12) + (size_t)n)*8 + s] : 0.0f;
    } else {
      wpx = w_pos[n]; wpy = w_pos[NN + n];
    }

    float a0 = g16sum(xkb4.x*qwbg4.x + xkb4.y*qwbg4.y + xkb4.z*qwbg4.z + xkb4.w*qwbg4.w);
    a0 = QSCALE*(a0 + qbbg);

    float a[4]; float lnv[4][4];
    #pragma unroll
    for (int k = 0; k < 4; ++k){
      const float rx = gx - poskx[k];
      const float ry = gy - posky[k];
      const float4 ge = make_float4(
          fmaf(rx, wgx4.x, fmaf(ry, wgy4.x, bgr4.x)),
          fmaf(rx, wgx4.y, fmaf(ry, wgy4.y, bgr4.y)),
          fmaf(rx, wgx4.z, fmaf(ry, wgy4.z, bgr4.z)),
          fmaf(rx, wgx4.w, fmaf(ry, wgy4.w, bgr4.w)));
      const float4 xk = make_float4(kf4.x+ge.x, kf4.y+ge.y, kf4.z+ge.z, kf4.w+ge.w);
      const float4 nk = ln16v(xk, lng4, lnb4);
      const float ak = g16sum(nk.x*qw4[k].x + nk.y*qw4[k].y + nk.z*qw4[k].z + nk.w*qw4[k].w);
      a[k] = QSCALE*(ak + qb[k]);
      const float4 xv = make_float4(vf4.x+ge.x, vf4.y+ge.y, vf4.z+ge.z, vf4.w+ge.w);
      const float4 nv = ln16v(xv, lng4, lnb4);
      lnv[k][0]=nv.x; lnv[k][1]=nv.y; lnv[k][2]=nv.z; lnv[k][3]=nv.w;
    }
    const float mx = fmaxf(fmaxf(fmaxf(a[0],a[1]), fmaxf(a[2],a[3])), a0);
    float p0 = __expf(a0 - mx);
    float pk[4];
    float sum = p0;
    #pragma unroll
    for (int k = 0; k < 4; ++k){ pk[k] = __expf(a[k]-mx); sum += pk[k]; }
    const float inv = 1.0f/sum;
    p0 = fmaf(p0, inv, ATT_EPS);
    #pragma unroll
    for (int k = 0; k < 4; ++k) pk[k] = fmaf(pk[k], inv, ATT_EPS);

    accS[0] += p0;
    accYbg[0] = fmaf(p0, xvb4.x, accYbg[0]);
    accYbg[1] = fmaf(p0, xvb4.y, accYbg[1]);
    accYbg[2] = fmaf(p0, xvb4.z, accYbg[2]);
    accYbg[3] = fmaf(p0, xvb4.w, accYbg[3]);
    if (LAST) accC[0] = fmaf(p0, fcv, accC[0]);
    #pragma unroll
    for (int k = 0; k < 4; ++k){
      accS[k+1] += pk[k];
      accY[k][0] = fmaf(pk[k], lnv[k][0], accY[k][0]);
      accY[k][1] = fmaf(pk[k], lnv[k][1], accY[k][1]);
      accY[k][2] = fmaf(pk[k], lnv[k][2], accY[k][2]);
      accY[k][3] = fmaf(pk[k], lnv[k][3], accY[k][3]);
      if (LAST){
        accC[k+1] = fmaf(pk[k], fcv, accC[k+1]);
      } else {
        accP[k][0] = fmaf(pk[k], gx, accP[k][0]);
        accP[k][1] = fmaf(pk[k], gy, accP[k][1]);
        accT[k][0] = fmaf(pk[k], wpx, accT[k][0]);
        accT[k][1] = fmaf(pk[k], wpy, accT[k][1]);
      }
    }
  }

  // cross-group (within-wave) reduction
  #pragma unroll
  for (int k = 0; k < 4; ++k){
    #pragma unroll
    for (int j = 0; j < 4; ++j){ float x = accY[k][j]; XRED(x); accY[k][j] = x; }
  }
  #pragma unroll
  for (int j = 0; j < 4; ++j){ float x = accYbg[j]; XRED(x); accYbg[j] = x; }
  #pragma unroll
  for (int sl = 0; sl < 5; ++sl){ float x = accS[sl]; XRED(x); accS[sl] = x; }
  #pragma unroll
  for (int sl = 0; sl < 5; ++sl){ float x = accC[sl]; XRED(x); accC[sl] = x; }
  #pragma unroll
  for (int k = 0; k < 4; ++k){
    float x;
    x = accP[k][0]; XRED(x); accP[k][0] = x;
    x = accP[k][1]; XRED(x); accP[k][1] = x;
    x = accT[k][0]; XRED(x); accT[k][0] = x;
    x = accT[k][1]; XRED(x); accT[k][1] = x;
  }

  const bool g0 = ((tid >> 4) & 3) == 0;
  if (g0){
    #pragma unroll
    for (int k = 0; k < 4; ++k){
      atomicAdd(&red[A_Y + k*64 + e0 + 0], accY[k][0]);
      atomicAdd(&red[A_Y + k*64 + e0 + 1], accY[k][1]);
      atomicAdd(&red[A_Y + k*64 + e0 + 2], accY[k][2]);
      atomicAdd(&red[A_Y + k*64 + e0 + 3], accY[k][3]);
    }
    atomicAdd(&red[A_YBG + e0 + 0], accYbg[0]);
    atomicAdd(&red[A_YBG + e0 + 1], accYbg[1]);
    atomicAdd(&red[A_YBG + e0 + 2], accYbg[2]);
    atomicAdd(&red[A_YBG + e0 + 3], accYbg[3]);
    if (s == 0){
      #pragma unroll
      for (int sl = 0; sl < 5; ++sl) atomicAdd(&red[A_S + sl], accS[sl]);
      if (!LAST){
        #pragma unroll
        for (int k = 0; k < 4; ++k){
          atomicAdd(&red[A_P + k*2 + 0], accP[k][0]);
          atomicAdd(&red[A_P + k*2 + 1], accP[k][1]);
          atomicAdd(&red[A_T + k*2 + 0], accT[k][0]);
          atomicAdd(&red[A_T + k*2 + 1], accT[k][1]);
        }
      }
    }
    if (LAST && s < 8){
      #pragma unroll
      for (int sl = 0; sl < 5; ++sl) atomicAdd(&red[A_C + sl*8 + s], accC[sl]);
    }
  }
  __syncthreads();
  float* gacc = ws + OFF_ACC + (size_t)b*384;
  for (int i = tid; i < 384; i += 256){
    const float v = red[i];
    if (v != 0.0f) atomicAdd(&gacc[i], v);
  }
}

// ---- per-iter slot update: upd-MLP, GRU, residual LN-MLP, pos ----
__global__ __launch_bounds__(64) void k_update(
    const float* __restrict__ w_mlp_fg, const float* __restrict__ b_mlp_fg,
    const float* __restrict__ w_mlp_bg, const float* __restrict__ b_mlp_bg,
    const float* __restrict__ gfg_wih, const float* __restrict__ gfg_whh,
    const float* __restrict__ gfg_bih, const float* __restrict__ gfg_bhh,
    const float* __restrict__ gbg_wih, const float* __restrict__ gbg_whh,
    const float* __restrict__ gbg_bih, const float* __restrict__ gbg_bhh,
    const float* __restrict__ ln_rfg_g, const float* __restrict__ ln_rfg_b,
    const float* __restrict__ w_rfg, const float* __restrict__ b_rfg,
    const float* __restrict__ ln_rbg_g, const float* __restrict__ ln_rbg_b,
    const float* __restrict__ w_rbg, const float* __restrict__ b_rbg,
    const float* __restrict__ b_pos, float* __restrict__ ws)
{
  const int b = blockIdx.x, d = threadIdx.x;
  float* acc = ws + OFF_ACC + (size_t)b*384;
  __shared__ float xl[64], hl[64], rl[64];
  for (int k = 0; k < 4; ++k){
    const float invS = 1.0f/acc[A_S + 1 + k];
    xl[d] = acc[A_Y + k*64 + d]*invS;
    __syncthreads();
    float upd = b_mlp_fg[d];
    for (int e = 0; e < 64; ++e) upd = fmaf(xl[e], w_mlp_fg[d*64+e], upd);
    const float h = ws[OFF_SFG + b*256 + k*64 + d];
    __syncthreads();
    xl[d] = upd; hl[d] = h;
    __syncthreads();
    float gir = gfg_bih[d], giz = gfg_bih[64+d], gin = gfg_bih[128+d];
    float ghr = gfg_bhh[d], ghz = gfg_bhh[64+d], ghn = gfg_bhh[128+d];
    for (int e = 0; e < 64; ++e){
      const float x = xl[e], hh = hl[e];
      gir = fmaf(x, gfg_wih[d*64+e], gir);
      giz = fmaf(x, gfg_wih[(64+d)*64+e], giz);
      gin = fmaf(x, gfg_wih[(128+d)*64+e], gin);
      ghr = fmaf(hh, gfg_whh[d*64+e], ghr);
      ghz = fmaf(hh, gfg_whh[(64+d)*64+e], ghz);
      ghn = fmaf(hh, gfg_whh[(128+d)*64+e], ghn);
    }
    const float r = 1.0f/(1.0f + expf(-(gir+ghr)));
    const float z = 1.0f/(1.0f + expf(-(giz+ghz)));
    const float nn = tanhf(fmaf(r, ghn, gin));
    const float hnew = (1.0f - z)*nn + z*h;
    const float m = wavesum(hnew)*(1.0f/64.0f);
    const float c = hnew - m;
    const float var = wavesum(c*c)*(1.0f/64.0f);
    const float rs = rsqrtf(var + LNEPS);
    rl[d] = c*rs*ln_rfg_g[d] + ln_rfg_b[d];
    __syncthreads();
    float outv = hnew + b_rfg[d];
    for (int e = 0; e < 64; ++e) outv = fmaf(rl[e], w_rfg[d*64+e], outv);
    ws[OFF_SFG + b*256 + k*64 + d] = outv;
    if (d < 2){
      const float P = acc[A_P + k*2 + d]*invS;
      const float T = acc[A_T + k*2 + d]*invS;
      float pn = P + tanhf(T + b_pos[d])*0.2f;
      pn = fminf(1.0f, fmaxf(-1.0f, pn));
      ws[OFF_POS + b*8 + k*2 + d] = pn;
    }
    __syncthreads();
  }
  {
    const float invS = 1.0f/acc[A_S + 0];
    xl[d] = acc[A_YBG + d]*invS;
    __syncthreads();
    float upd = b_mlp_bg[d];
    for (int e = 0; e < 64; ++e) upd = fmaf(xl[e], w_mlp_bg[d*64+e], upd);
    const float h = ws[OFF_SBG + b*64 + d];
    __syncthreads();
    xl[d] = upd; hl[d] = h;
    __syncthreads();
    float gir = gbg_bih[d], giz = gbg_bih[64+d], gin = gbg_bih[128+d];
    float ghr = gbg_bhh[d], ghz = gbg_bhh[64+d], ghn = gbg_bhh[128+d];
    for (int e = 0; e < 64; ++e){
      const float x = xl[e], hh = hl[e];
      gir = fmaf(x, gbg_wih[d*64+e], gir);
      giz = fmaf(x, gbg_wih[(64+d)*64+e], giz);
      gin = fmaf(x, gbg_wih[(128+d)*64+e], gin);
      ghr = fmaf(hh, gbg_whh[d*64+e], ghr);
      ghz = fmaf(hh, gbg_whh[(64+d)*64+e], ghz);
      ghn = fmaf(hh, gbg_whh[(128+d)*64+e], ghn);
    }
    const float r = 1.0f/(1.0f + expf(-(gir+ghr)));
    const float z = 1.0f/(1.0f + expf(-(giz+ghz)));
    const float nn = tanhf(fmaf(r, ghn, gin));
    const float hnew = (1.0f - z)*nn + z*h;
    const float m = wavesum(hnew)*(1.0f/64.0f);
    const float c = hnew - m;
    const float var = wavesum(c*c)*(1.0f/64.0f);
    const float rs = rsqrtf(var + LNEPS);
    rl[d] = c*rs*ln_rbg_g[d] + ln_rbg_b[d];
    __syncthreads();
    float outv = hnew + b_rbg[d];
    for (int e = 0; e < 64; ++e) outv = fmaf(rl[e], w_rbg[d*64+e], outv);
    ws[OFF_SBG + b*64 + d] = outv;
  }
}

// ---- final output kernel ----
__global__ __launch_bounds__(64) void k_final(
    const float* __restrict__ w_mlp_fg, const float* __restrict__ b_mlp_fg,
    const float* __restrict__ w_mlp_bg, const float* __restrict__ b_mlp_bg,
    const float* __restrict__ ws, float* __restrict__ out)
{
  const int b = blockIdx.x, d = threadIdx.x;
  const float* acc = ws + OFF_ACC + (size_t)b*384;
  __shared__ float xl[64];
  {
    const float invS = 1.0f/acc[A_S];
    xl[d] = acc[A_YBG + d]*invS;
    __syncthreads();
    float o = b_mlp_bg[d];
    for (int e = 0; e < 64; ++e) o = fmaf(xl[e], w_mlp_bg[d*64+e], o);
    out[(b*5 + 0)*72 + d] = o;
    if (d < 8) out[(b*5 + 0)*72 + 64 + d] = acc[A_C + d]*invS;
    __syncthreads();
  }
  for (int k = 0; k < 4; ++k){
    const float invS = 1.0f/acc[A_S + 1 + k];
    xl[d] = acc[A_Y + k*64 + d]*invS;
    __syncthreads();
    float o = b_mlp_fg[d];
    for (int e = 0; e < 64; ++e) o = fmaf(xl[e], w_mlp_fg[d*64+e], o);
    out[(b*5 + 1 + k)*72 + d] = o;
    if (d < 8) out[(b*5 + 1 + k)*72 + 64 + d] = acc[A_C + (k+1)*8 + d]*invS;
    __syncthreads();
  }
}

extern "C" void kernel_launch(void* const* d_in, const int* in_sizes, int n_in,
                              void* d_out, int out_size, void* d_ws, size_t ws_size,
                              hipStream_t stream)
{
  const float* feat          = (const float*)d_in[0];
  const float* feat_color    = (const float*)d_in[1];
  const float* w_grid        = (const float*)d_in[2];
  const float* b_grid        = (const float*)d_in[3];
  const float* w_kfg         = (const float*)d_in[4];
  const float* w_vfg         = (const float*)d_in[5];
  const float* w_kbg         = (const float*)d_in[6];
  const float* w_vbg         = (const float*)d_in[7];
  const float* ln_fg_g       = (const float*)d_in[8];
  const float* ln_fg_b       = (const float*)d_in[9];
  const float* w_mlp_fg      = (const float*)d_in[10];
  const float* b_mlp_fg      = (const float*)d_in[11];
  const float* ln_bg_g       = (const float*)d_in[12];
  const float* ln_bg_b       = (const float*)d_in[13];
  const float* w_mlp_bg      = (const float*)d_in[14];
  const float* b_mlp_bg      = (const float*)d_in[15];
  const float* slots_init_fg = (const float*)d_in[16];
  const float* slots_init_bg = (const float*)d_in[17];
  const float* fg_position   = (const float*)d_in[18];
  const float* w_pos         = (const float*)d_in[19];
  const float* b_pos         = (const float*)d_in[20];
  const float* ln_q_g        = (const float*)d_in[21];
  const float* ln_q_b        = (const float*)d_in[22];
  const float* w_q           = (const float*)d_in[23];
  const float* ln_qbg_g      = (const float*)d_in[24];
  const float* ln_qbg_b      = (const float*)d_in[25];
  const float* w_qbg         = (const float*)d_in[26];
  const float* gfg_wih       = (const float*)d_in[27];
  const float* gfg_whh       = (const float*)d_in[28];
  const float* gfg_bih       = (const float*)d_in[29];
  const float* gfg_bhh       = (const float*)d_in[30];
  const float* gbg_wih       = (const float*)d_in[31];
  const float* gbg_whh       = (const float*)d_in[32];
  const float* gbg_bih       = (const float*)d_in[33];
  const float* gbg_bhh       = (const float*)d_in[34];
  const float* ln_rfg_g      = (const float*)d_in[35];
  const float* ln_rfg_b      = (const float*)d_in[36];
  const float* w_rfg         = (const float*)d_in[37];
  const float* b_rfg         = (const float*)d_in[38];
  const float* ln_rbg_g      = (const float*)d_in[39];
  const float* ln_rbg_b      = (const float*)d_in[40];
  const float* w_rbg         = (const float*)d_in[41];
  const float* b_rbg         = (const float*)d_in[42];
  const float* ln_feat_g     = (const float*)d_in[43];
  const float* ln_feat_b     = (const float*)d_in[44];
  const float* ln_fc_g       = (const float*)d_in[45];
  const float* ln_fc_b       = (const float*)d_in[46];
  float* ws  = (float*)d_ws;
  float* out = (float*)d_out;

  hipLaunchKernelGGL(k_fcln, dim3(256), dim3(256), 0, stream,
                     feat_color, ln_fc_g, ln_fc_b, ws);
  hipLaunchKernelGGL(k_pre, dim3(1024), dim3(256), 0, stream,
                     feat, w_kfg, w_vfg, w_kbg, w_vbg, w_grid, b_grid,
                     ln_feat_g, ln_feat_b, ln_bg_g, ln_bg_b, ws);
  hipLaunchKernelGGL(k_init, dim3(16), dim3(256), 0, stream,
                     slots_init_fg, slots_init_bg, fg_position, ws);
  for (int it = 0; it < NITER; ++it){
    hipLaunchKernelGGL(k_prep, dim3(16), dim3(64), 0, stream,
                       ln_q_g, ln_q_b, w_q, ln_qbg_g, ln_qbg_b, w_qbg,
                       w_mlp_fg, b_mlp_fg, w_mlp_bg, b_mlp_bg, ws);
    if (it < NITER-1){
      hipLaunchKernelGGL((k_main<0>), dim3(64,16), dim3(256), 0, stream,
                         w_grid, b_grid, ln_fg_g, ln_fg_b, w_pos, ws);
      hipLaunchKernelGGL(k_update, dim3(16), dim3(64), 0, stream,
                         w_mlp_fg, b_mlp_fg, w_mlp_bg, b_mlp_bg,
                         gfg_wih, gfg_whh, gfg_bih, gfg_bhh,
                         gbg_wih, gbg_whh, gbg_bih, gbg_bhh,
                         ln_rfg_g, ln_rfg_b, w_rfg, b_rfg,
                         ln_rbg_g, ln_rbg_b, w_rbg, b_rbg,
                         b_pos, ws);
    } else {
      hipLaunchKernelGGL((k_main<1>), dim3(64,16), dim3(256), 0, stream,
                         w_grid, b_grid, ln_fg_g, ln_fg_b, w_pos, ws);
      hipLaunchKernelGGL(k_final, dim3(16), dim3(64), 0, stream,
                         w_mlp_fg, b_mlp_fg, w_mlp_bg, b_mlp_bg, ws, out);
    }
  }
}

// Round 5
// 204.008 us; speedup vs baseline: 3.6567x; 1.8265x over previous
//
#include <hip/hip_runtime.h>
#include <math.h>
#include <stddef.h>

#define NB 16
#define ND 64
#define NN 4096
#define NCD 8
#define NITER 4
#define ATT_EPS 1e-8f
#define LNEPS 1e-5f
#define QSCALE 0.125f

// ---- workspace layout (float offsets) ----
static constexpr size_t SZ_MAT   = (size_t)NB*NN*ND;           // 4194304
static constexpr size_t OFF_UK   = 0;                          // (kf+bgr centered)*g
static constexpr size_t OFF_CV0  = OFF_UK   + SZ_MAT;          // vf+bgr centered (raw)
static constexpr size_t OFF_XKBG = OFF_CV0  + SZ_MAT;          // LN'd bg k pre-MLP
static constexpr size_t OFF_XVBG = OFF_XKBG + SZ_MAT;          // LN'd bg v pre-MLP
static constexpr size_t OFF_SCAL = OFF_XVBG + SZ_MAT;          // per-token 8: Sk0,2Skx,2Sky,0,Sv0,2Svx,2Svy,0
static constexpr size_t OFF_ACC  = OFF_SCAL + (size_t)NB*NN*8; // NB*448
static constexpr size_t OFF_SFG  = OFF_ACC  + (size_t)NB*448;
static constexpr size_t OFF_SBG  = OFF_SFG  + (size_t)NB*256;
static constexpr size_t OFF_POS  = OFF_SBG  + (size_t)NB*64;
static constexpr size_t OFF_QW   = OFF_POS  + (size_t)NB*8;
static constexpr size_t OFF_QWBG = OFF_QW   + (size_t)NB*256;
static constexpr size_t OFF_QBBG = OFF_QWBG + (size_t)NB*64;
static constexpr size_t OFF_ABC  = OFF_QBBG + (size_t)NB;      // per (b,k): A,B,C,pad
static constexpr size_t OFF_CXG  = OFF_ABC  + (size_t)NB*16;   // cx*g (64)
static constexpr size_t OFF_CYG  = OFF_CXG  + 64;              // cy*g (64)
static constexpr size_t OFF_GS   = OFF_CYG  + 64;              // Gxx,Gyy,2*Gxy

// per-b accumulator layout (stride 448)
#define A_S 0
#define A_W0 8
#define A_WX 12
#define A_WY 16
#define A_P 24
#define A_T 32
#define A_C 40
#define A_Y 80
#define A_YBG 336
#define ACC_STRIDE 448

// ---- helpers ----
__device__ __forceinline__ float g16sum(float x){
  x += __shfl_xor(x, 1);
  x += __shfl_xor(x, 2);
  x += __shfl_xor(x, 4);
  x += __shfl_xor(x, 8);
  return x;
}
__device__ __forceinline__ float wavesum(float x){
  x += __shfl_xor(x, 1);  x += __shfl_xor(x, 2);
  x += __shfl_xor(x, 4);  x += __shfl_xor(x, 8);
  x += __shfl_xor(x, 16); x += __shfl_xor(x, 32);
  return x;
}
__device__ __forceinline__ float4 f4fma(float a, float4 w, float4 c){
  c.x = fmaf(a, w.x, c.x); c.y = fmaf(a, w.y, c.y);
  c.z = fmaf(a, w.z, c.z); c.w = fmaf(a, w.w, c.w);
  return c;
}
__device__ __forceinline__ float dot4(float4 a, float4 b){
  return fmaf(a.x,b.x, fmaf(a.y,b.y, fmaf(a.z,b.z, a.w*b.w)));
}
// 64-dim LayerNorm over a 16-lane group (4 elems/lane), returns g*xhat+b
__device__ __forceinline__ float4 ln16v(float4 x, float4 g, float4 bb){
  float m = g16sum(x.x + x.y + x.z + x.w) * (1.0f/64.0f);
  float4 c = make_float4(x.x - m, x.y - m, x.z - m, x.w - m);
  float var = g16sum(c.x*c.x + c.y*c.y + c.z*c.z + c.w*c.w) * (1.0f/64.0f);
  float rs = rsqrtf(var + LNEPS);
  return make_float4(c.x*rs*g.x + bb.x, c.y*rs*g.y + bb.y,
                     c.z*rs*g.z + bb.z, c.w*rs*g.w + bb.w);
}
// row-major 64-dot: W row (global, 16B-aligned) . x (LDS)
__device__ __forceinline__ float rowdot64(const float* __restrict__ W, const float* x){
  const float4* w4 = (const float4*)W;
  const float4* x4 = (const float4*)x;
  float s = 0.0f;
  #pragma unroll
  for (int t = 0; t < 16; ++t){
    float4 w = w4[t], xx = x4[t];
    s = fmaf(w.x,xx.x, fmaf(w.y,xx.y, fmaf(w.z,xx.z, fmaf(w.w,xx.w, s))));
  }
  return s;
}
#define XRED(x) do { x += __shfl_xor(x, 16); x += __shfl_xor(x, 32); } while (0)

// ---- kernel: precompute uk, cv0, scal (fg half) and xkbg, xvbg (bg half) ----
// grid = 2048 x 256. half = bid>>10. 64 tokens/block, 128 cols (2 matrices).
__global__ __launch_bounds__(256) void k_pre(
    const float* __restrict__ feat,
    const float* __restrict__ w_kfg, const float* __restrict__ w_vfg,
    const float* __restrict__ w_kbg, const float* __restrict__ w_vbg,
    const float* __restrict__ w_grid, const float* __restrict__ b_grid,
    const float* __restrict__ ln_feat_g, const float* __restrict__ ln_feat_b,
    const float* __restrict__ ln_bg_g, const float* __restrict__ ln_bg_b,
    const float* __restrict__ ln_fg_g,
    float* __restrict__ ws)
{
  __shared__ float fl[64][68];       // LN'd feat tile
  __shared__ float wl[2][64][68];    // weights^T  wl[m][e][d] = W_m[d][e]
  const int tid  = threadIdx.x;
  const int bid  = blockIdx.x;
  const int half = bid >> 10;        // 0 = fg pair, 1 = bg pair
  const int tb   = bid & 1023;       // token-block (64 tokens)
  const int i    = tid >> 4;         // 0..15 token-group
  const int j    = tid & 15;         // 0..15 col-group
  const int e0j  = 4*j;
  const float* wA = half ? w_kbg : w_kfg;
  const float* wB = half ? w_vbg : w_vfg;

  // stage weights transposed
  #pragma unroll
  for (int it = 0; it < 8; ++it){
    const int f = it*256 + tid;       // float4 id 0..2047
    const int m = f >> 10;
    const int r = f & 1023;
    const int d = r >> 4;
    const int s4 = r & 15;
    const float* src = m ? wB : wA;
    const float4 wv = *(const float4*)(src + d*64 + 4*s4);
    wl[m][4*s4+0][d] = wv.x;
    wl[m][4*s4+1][d] = wv.y;
    wl[m][4*s4+2][d] = wv.z;
    wl[m][4*s4+3][d] = wv.w;
  }
  // stage feat tile with LN
  {
    const float4 lfg4 = *(const float4*)(ln_feat_g + e0j);
    const float4 lfb4 = *(const float4*)(ln_feat_b + e0j);
    #pragma unroll
    for (int it = 0; it < 4; ++it){
      const int tok = it*16 + i;
      const size_t gb = ((size_t)tb*64 + tok)*64 + e0j;
      const float4 f4 = *(const float4*)(feat + gb);
      *(float4*)&fl[tok][e0j] = ln16v(f4, lfg4, lfb4);
    }
  }
  __syncthreads();

  float4 acc0[4], acc1[4];
  #pragma unroll
  for (int u = 0; u < 4; ++u){ acc0[u] = make_float4(0,0,0,0); acc1[u] = acc0[u]; }
  for (int e0 = 0; e0 < 64; e0 += 4){
    float4 a[4];
    #pragma unroll
    for (int u = 0; u < 4; ++u) a[u] = *(const float4*)&fl[u*16 + i][e0];
    #pragma unroll
    for (int l = 0; l < 4; ++l){
      const float4 b0 = *(const float4*)&wl[0][e0+l][e0j];
      const float4 b1 = *(const float4*)&wl[1][e0+l][e0j];
      #pragma unroll
      for (int u = 0; u < 4; ++u){
        const float av = l==0 ? a[u].x : l==1 ? a[u].y : l==2 ? a[u].z : a[u].w;
        acc0[u] = f4fma(av, b0, acc0[u]);
        acc1[u] = f4fma(av, b1, acc1[u]);
      }
    }
  }

  const float4 bgr4 = *(const float4*)(b_grid + e0j);
  float4 wgx4, wgy4;
  {
    float4 w0 = *(const float4*)(w_grid + (e0j+0)*4);
    float4 w1 = *(const float4*)(w_grid + (e0j+1)*4);
    float4 w2 = *(const float4*)(w_grid + (e0j+2)*4);
    float4 w3 = *(const float4*)(w_grid + (e0j+3)*4);
    wgx4 = make_float4(w0.x-w0.z, w1.x-w1.z, w2.x-w2.z, w3.x-w3.z);
    wgy4 = make_float4(w0.y-w0.w, w1.y-w1.w, w2.y-w2.w, w3.y-w3.w);
  }

  if (!half){
    // fg: centered stats + u = c0*g, cv0 raw
    const float4 lng4 = *(const float4*)(ln_fg_g + e0j);
    const float mx = g16sum(wgx4.x+wgx4.y+wgx4.z+wgx4.w)*(1.0f/64.0f);
    const float my = g16sum(wgy4.x+wgy4.y+wgy4.z+wgy4.w)*(1.0f/64.0f);
    const float4 cx4 = make_float4(wgx4.x-mx, wgx4.y-mx, wgx4.z-mx, wgx4.w-mx);
    const float4 cy4 = make_float4(wgy4.x-my, wgy4.y-my, wgy4.z-my, wgy4.w-my);
    float* uk  = ws + OFF_UK;
    float* cv0 = ws + OFF_CV0;
    #pragma unroll
    for (int u = 0; u < 4; ++u){
      const size_t t = (size_t)tb*64 + u*16 + i;
      const size_t fb = t*64 + e0j;
      // k-side
      float4 kb = make_float4(acc0[u].x+bgr4.x, acc0[u].y+bgr4.y, acc0[u].z+bgr4.z, acc0[u].w+bgr4.w);
      float mk = g16sum(kb.x+kb.y+kb.z+kb.w)*(1.0f/64.0f);
      float4 c0 = make_float4(kb.x-mk, kb.y-mk, kb.z-mk, kb.w-mk);
      float sk0 = g16sum(dot4(c0,c0));
      float skx = g16sum(dot4(c0,cx4));
      float sky = g16sum(dot4(c0,cy4));
      *(float4*)(uk + fb) = make_float4(c0.x*lng4.x, c0.y*lng4.y, c0.z*lng4.z, c0.w*lng4.w);
      // v-side
      float4 vb = make_float4(acc1[u].x+bgr4.x, acc1[u].y+bgr4.y, acc1[u].z+bgr4.z, acc1[u].w+bgr4.w);
      float mv = g16sum(vb.x+vb.y+vb.z+vb.w)*(1.0f/64.0f);
      float4 cv = make_float4(vb.x-mv, vb.y-mv, vb.z-mv, vb.w-mv);
      float sv0 = g16sum(dot4(cv,cv));
      float svx = g16sum(dot4(cv,cx4));
      float svy = g16sum(dot4(cv,cy4));
      *(float4*)(cv0 + fb) = cv;
      if (j == 0){
        float* sc = ws + OFF_SCAL + t*8;
        *(float4*)(sc)   = make_float4(sk0, 2.0f*skx, 2.0f*sky, 0.0f);
        *(float4*)(sc+4) = make_float4(sv0, 2.0f*svx, 2.0f*svy, 0.0f);
      }
    }
  } else {
    // bg: ge + LN(ln_bg), store LN'd pre-MLP vectors
    const float4 lbg4 = *(const float4*)(ln_bg_g + e0j);
    const float4 lbb4 = *(const float4*)(ln_bg_b + e0j);
    float* xkbg = ws + OFF_XKBG;
    float* xvbg = ws + OFF_XVBG;
    #pragma unroll
    for (int u = 0; u < 4; ++u){
      const size_t t = (size_t)tb*64 + u*16 + i;
      const int n = (int)(t & (NN-1));
      const float gx = -1.0f + (2.0f/63.0f)*(float)(n & 63);
      const float gy = -1.0f + (2.0f/63.0f)*(float)(n >> 6);
      const float4 ge = make_float4(
          fmaf(gx, wgx4.x, fmaf(gy, wgy4.x, bgr4.x)),
          fmaf(gx, wgx4.y, fmaf(gy, wgy4.y, bgr4.y)),
          fmaf(gx, wgx4.z, fmaf(gy, wgy4.z, bgr4.z)),
          fmaf(gx, wgx4.w, fmaf(gy, wgy4.w, bgr4.w)));
      const size_t fb = t*64 + e0j;
      float4 xk = make_float4(acc0[u].x+ge.x, acc0[u].y+ge.y, acc0[u].z+ge.z, acc0[u].w+ge.w);
      *(float4*)(xkbg + fb) = ln16v(xk, lbg4, lbb4);
      float4 xv = make_float4(acc1[u].x+ge.x, acc1[u].y+ge.y, acc1[u].z+ge.z, acc1[u].w+ge.w);
      *(float4*)(xvbg + fb) = ln16v(xv, lbg4, lbb4);
    }
  }
}

// ---- kernel: init slot state + grid-direction constants ----
__global__ void k_init(const float* __restrict__ sfg0, const float* __restrict__ sbg0,
                       const float* __restrict__ pos0, const float* __restrict__ w_grid,
                       const float* __restrict__ ln_fg_g, float* __restrict__ ws){
  const int t = blockIdx.x*256 + threadIdx.x;
  if (t < NB*256) ws[OFF_SFG + t] = sfg0[t & 255];
  if (t < NB*64)  ws[OFF_SBG + t] = sbg0[t & 63];
  if (t < NB*8)   ws[OFF_POS + t] = pos0[t & 7];
  if (blockIdx.x == 0 && threadIdx.x < 64){
    const int d = threadIdx.x;
    const float wgx = w_grid[4*d] - w_grid[4*d+2];
    const float wgy = w_grid[4*d+1] - w_grid[4*d+3];
    const float mx = wavesum(wgx)*(1.0f/64.0f);
    const float my = wavesum(wgy)*(1.0f/64.0f);
    const float cx = wgx - mx, cy = wgy - my;
    ws[OFF_CXG + d] = cx*ln_fg_g[d];
    ws[OFF_CYG + d] = cy*ln_fg_g[d];
    const float gxx = wavesum(cx*cx);
    const float gyy = wavesum(cy*cy);
    const float gxy = wavesum(cx*cy);
    if (d == 0){ ws[OFF_GS] = gxx; ws[OFF_GS+1] = gyy; ws[OFF_GS+2] = 2.0f*gxy; }
  }
}

// ---- kernel: per-iter q folding. grid (5,16) x 64 ----
__global__ __launch_bounds__(64) void k_prep(
    const float* __restrict__ ln_q_g, const float* __restrict__ ln_q_b,
    const float* __restrict__ w_q,
    const float* __restrict__ ln_qbg_g, const float* __restrict__ ln_qbg_b,
    const float* __restrict__ w_qbg,
    const float* __restrict__ w_mlp_fg, const float* __restrict__ b_mlp_fg,
    const float* __restrict__ w_mlp_bg, const float* __restrict__ b_mlp_bg,
    const float* __restrict__ ln_fg_b,
    float* __restrict__ ws)
{
  const int k = blockIdx.x, b = blockIdx.y, d = threadIdx.x;
  __shared__ float qin[64], qv[64];
  if (k == 0){
    float* acc = ws + OFF_ACC + (size_t)b*ACC_STRIDE;
    for (int i2 = d; i2 < ACC_STRIDE; i2 += 64) acc[i2] = 0.0f;
  }
  if (k < 4){
    const float sv = ws[OFF_SFG + b*256 + k*64 + d];
    const float m = wavesum(sv)*(1.0f/64.0f);
    const float c = sv - m;
    const float var = wavesum(c*c)*(1.0f/64.0f);
    const float rs = rsqrtf(var + LNEPS);
    qin[d] = c*rs*ln_q_g[d] + ln_q_b[d];
    __syncthreads();
    const float q = rowdot64(w_q + d*64, qin);
    qv[d] = q;
    const float qb = wavesum(q * b_mlp_fg[d]);
    __syncthreads();
    float qw = 0.0f;
    for (int e = 0; e < 64; ++e) qw = fmaf(qv[e], w_mlp_fg[e*64+d], qw);
    ws[OFF_QW + b*256 + k*64 + d] = qw;
    const float A  = wavesum(qw * ws[OFF_CXG + d]);
    const float Bv = wavesum(qw * ws[OFF_CYG + d]);
    const float Cv = wavesum(qw * ln_fg_b[d]) + qb;
    if (d == 0){
      float* abc = ws + OFF_ABC + (size_t)(b*4 + k)*4;
      abc[0] = A; abc[1] = Bv; abc[2] = Cv;
    }
  } else {
    const float sv = ws[OFF_SBG + b*64 + d];
    const float m = wavesum(sv)*(1.0f/64.0f);
    const float c = sv - m;
    const float var = wavesum(c*c)*(1.0f/64.0f);
    const float rs = rsqrtf(var + LNEPS);
    qin[d] = c*rs*ln_qbg_g[d] + ln_qbg_b[d];
    __syncthreads();
    const float q = rowdot64(w_qbg + d*64, qin);
    qv[d] = q;
    const float qb = wavesum(q * b_mlp_bg[d]);
    __syncthreads();
    float qw = 0.0f;
    for (int e = 0; e < 64; ++e) qw = fmaf(qv[e], w_mlp_bg[e*64+d], qw);
    ws[OFF_QWBG + b*64 + d] = qw;
    if (d == 0) ws[OFF_QBBG + b] = qb;
  }
}

// ---- main fused attention pass. grid (64,16) x 256 ----
template<int LAST>
__global__ __launch_bounds__(256) void k_main(
    const float* __restrict__ fc, const float* __restrict__ fcg,
    const float* __restrict__ fcb, const float* __restrict__ w_pos,
    float* __restrict__ ws)
{
  __shared__ float red[ACC_STRIDE];
  const int tid = threadIdx.x;
  const int b = blockIdx.y;
  for (int i2 = tid; i2 < ACC_STRIDE; i2 += 256) red[i2] = 0.0f;
  __syncthreads();

  const int G = tid >> 4;
  const int s = tid & 15;
  const int e0 = 4*s;

  float4 qw4[4]; float A[4], Bc[4], Cc[4], px[4], py[4];
  #pragma unroll
  for (int k = 0; k < 4; ++k){
    qw4[k] = *(const float4*)(ws + OFF_QW + (size_t)b*256 + k*64 + e0);
    const float* abc = ws + OFF_ABC + (size_t)(b*4 + k)*4;
    A[k] = abc[0]; Bc[k] = abc[1]; Cc[k] = abc[2];
    px[k] = ws[OFF_POS + b*8 + k*2 + 0];
    py[k] = ws[OFF_POS + b*8 + k*2 + 1];
  }
  const float4 qwbg4 = *(const float4*)(ws + OFF_QWBG + (size_t)b*64 + e0);
  const float qbbg = ws[OFF_QBBG + b];
  const float Gxx = ws[OFF_GS], Gyy = ws[OFF_GS+1], Gxy2 = ws[OFF_GS+2];

  const float* uk   = ws + OFF_UK;
  const float* cv0  = ws + OFF_CV0;
  const float* xkbg = ws + OFF_XKBG;
  const float* xvbg = ws + OFF_XVBG;

  float accY[4][4] = {};
  float accYbg[4] = {};
  float accS[5] = {};
  float accW0[4] = {}, accWx[4] = {}, accWy[4] = {};
  float accP[4][2] = {};
  float accT[4][2] = {};
  float accC[5] = {};

  const int nbase = blockIdx.x*64 + G*4;
  for (int i = 0; i < 4; ++i){
    const int n = nbase + i;
    const size_t tok = ((size_t)b << 12) + (size_t)n;
    const size_t rbase = tok*64 + e0;
    const float4 uk4  = *(const float4*)(uk + rbase);
    const float4 cv4  = *(const float4*)(cv0 + rbase);
    const float4 xkb4 = *(const float4*)(xkbg + rbase);
    const float4 xvb4 = *(const float4*)(xvbg + rbase);
    const float4 sA = *(const float4*)(ws + OFF_SCAL + tok*8);
    const float4 sB = *(const float4*)(ws + OFF_SCAL + tok*8 + 4);
    const float gx = -1.0f + (2.0f/63.0f)*(float)(n & 63);
    const float gy = -1.0f + (2.0f/63.0f)*(float)(n >> 6);
    float fcv = 0.0f, wpx = 0.0f, wpy = 0.0f;
    if (LAST){
      float v = (s < 8) ? fc[tok*8 + s] : 0.0f;
      float m8 = v;
      m8 += __shfl_xor(m8, 1); m8 += __shfl_xor(m8, 2); m8 += __shfl_xor(m8, 4);
      m8 *= 0.125f;
      const float cc = v - m8;
      float va = cc*cc;
      va += __shfl_xor(va, 1); va += __shfl_xor(va, 2); va += __shfl_xor(va, 4);
      va *= 0.125f;
      const float rs8 = rsqrtf(va + LNEPS);
      fcv = (s < 8) ? cc*rs8*fcg[s] + fcb[s] : 0.0f;
    } else {
      wpx = w_pos[n]; wpy = w_pos[NN + n];
    }

    float a0 = g16sum(dot4(xkb4, qwbg4));
    a0 = QSCALE*(a0 + qbbg);

    float a[4], rsv[4];
    #pragma unroll
    for (int k = 0; k < 4; ++k){
      const float rx = gx - px[k];
      const float ry = gy - py[k];
      const float rxy = rx*ry;
      // k-side var*64
      float h1 = fmaf(rx, Gxx, sA.y);
      float h2 = fmaf(ry, Gyy, sA.z);
      float vk = fmaf(rx, h1, fmaf(ry, h2, sA.x));
      vk = fmaf(rxy, Gxy2, vk);
      const float rsk = rsqrtf(fmaf(vk, 1.0f/64.0f, LNEPS));
      // v-side var*64
      float h1v = fmaf(rx, Gxx, sB.y);
      float h2v = fmaf(ry, Gyy, sB.z);
      float vv = fmaf(rx, h1v, fmaf(ry, h2v, sB.x));
      vv = fmaf(rxy, Gxy2, vv);
      rsv[k] = rsqrtf(fmaf(vv, 1.0f/64.0f, LNEPS));
      float dk = g16sum(dot4(uk4, qw4[k]));
      dk = fmaf(rx, A[k], dk);
      dk = fmaf(ry, Bc[k], dk);
      a[k] = QSCALE * fmaf(rsk, dk, Cc[k]);
    }
    const float mx = fmaxf(fmaxf(fmaxf(a[0],a[1]), fmaxf(a[2],a[3])), a0);
    float p0 = __expf(a0 - mx);
    float pk[4];
    float sum = p0;
    #pragma unroll
    for (int k = 0; k < 4; ++k){ pk[k] = __expf(a[k]-mx); sum += pk[k]; }
    const float inv = 1.0f/sum;
    p0 = fmaf(p0, inv, ATT_EPS);
    #pragma unroll
    for (int k = 0; k < 4; ++k) pk[k] = fmaf(pk[k], inv, ATT_EPS);

    accS[0] += p0;
    accYbg[0] = fmaf(p0, xvb4.x, accYbg[0]);
    accYbg[1] = fmaf(p0, xvb4.y, accYbg[1]);
    accYbg[2] = fmaf(p0, xvb4.z, accYbg[2]);
    accYbg[3] = fmaf(p0, xvb4.w, accYbg[3]);
    if (LAST) accC[0] = fmaf(p0, fcv, accC[0]);
    #pragma unroll
    for (int k = 0; k < 4; ++k){
      accS[k+1] += pk[k];
      const float prv = pk[k]*rsv[k];
      accY[k][0] = fmaf(prv, cv4.x, accY[k][0]);
      accY[k][1] = fmaf(prv, cv4.y, accY[k][1]);
      accY[k][2] = fmaf(prv, cv4.z, accY[k][2]);
      accY[k][3] = fmaf(prv, cv4.w, accY[k][3]);
      accW0[k] += prv;
      accWx[k] = fmaf(prv, gx, accWx[k]);
      accWy[k] = fmaf(prv, gy, accWy[k]);
      if (LAST){
        accC[k+1] = fmaf(pk[k], fcv, accC[k+1]);
      } else {
        accP[k][0] = fmaf(pk[k], gx, accP[k][0]);
        accP[k][1] = fmaf(pk[k], gy, accP[k][1]);
        accT[k][0] = fmaf(pk[k], wpx, accT[k][0]);
        accT[k][1] = fmaf(pk[k], wpy, accT[k][1]);
      }
    }
  }

  // cross-group (within-wave) reduction
  #pragma unroll
  for (int k = 0; k < 4; ++k){
    #pragma unroll
    for (int j2 = 0; j2 < 4; ++j2){ float x = accY[k][j2]; XRED(x); accY[k][j2] = x; }
    float x;
    x = accW0[k]; XRED(x); accW0[k] = x;
    x = accWx[k]; XRED(x); accWx[k] = x;
    x = accWy[k]; XRED(x); accWy[k] = x;
    x = accP[k][0]; XRED(x); accP[k][0] = x;
    x = accP[k][1]; XRED(x); accP[k][1] = x;
    x = accT[k][0]; XRED(x); accT[k][0] = x;
    x = accT[k][1]; XRED(x); accT[k][1] = x;
  }
  #pragma unroll
  for (int j2 = 0; j2 < 4; ++j2){ float x = accYbg[j2]; XRED(x); accYbg[j2] = x; }
  #pragma unroll
  for (int sl = 0; sl < 5; ++sl){ float x = accS[sl]; XRED(x); accS[sl] = x; }
  #pragma unroll
  for (int sl = 0; sl < 5; ++sl){ float x = accC[sl]; XRED(x); accC[sl] = x; }

  const bool g0 = (G & 3) == 0;
  if (g0){
    #pragma unroll
    for (int k = 0; k < 4; ++k){
      atomicAdd(&red[A_Y + k*64 + e0 + 0], accY[k][0]);
      atomicAdd(&red[A_Y + k*64 + e0 + 1], accY[k][1]);
      atomicAdd(&red[A_Y + k*64 + e0 + 2], accY[k][2]);
      atomicAdd(&red[A_Y + k*64 + e0 + 3], accY[k][3]);
    }
    atomicAdd(&red[A_YBG + e0 + 0], accYbg[0]);
    atomicAdd(&red[A_YBG + e0 + 1], accYbg[1]);
    atomicAdd(&red[A_YBG + e0 + 2], accYbg[2]);
    atomicAdd(&red[A_YBG + e0 + 3], accYbg[3]);
    if (s == 0){
      #pragma unroll
      for (int sl = 0; sl < 5; ++sl) atomicAdd(&red[A_S + sl], accS[sl]);
      #pragma unroll
      for (int k = 0; k < 4; ++k){
        atomicAdd(&red[A_W0 + k], accW0[k]);
        atomicAdd(&red[A_WX + k], accWx[k]);
        atomicAdd(&red[A_WY + k], accWy[k]);
      }
      if (!LAST){
        #pragma unroll
        for (int k = 0; k < 4; ++k){
          atomicAdd(&red[A_P + k*2 + 0], accP[k][0]);
          atomicAdd(&red[A_P + k*2 + 1], accP[k][1]);
          atomicAdd(&red[A_T + k*2 + 0], accT[k][0]);
          atomicAdd(&red[A_T + k*2 + 1], accT[k][1]);
        }
      }
    }
    if (LAST && s < 8){
      #pragma unroll
      for (int sl = 0; sl < 5; ++sl) atomicAdd(&red[A_C + sl*8 + s], accC[sl]);
    }
  }
  __syncthreads();
  float* gacc = ws + OFF_ACC + (size_t)b*ACC_STRIDE;
  for (int i2 = tid; i2 < ACC_STRIDE; i2 += 256){
    const float v = red[i2];
    if (v != 0.0f) atomicAdd(&gacc[i2], v);
  }
}

// ---- per-iter slot update. grid (5,16) x 64 ----
__global__ __launch_bounds__(64) void k_update(
    const float* __restrict__ w_mlp_fg, const float* __restrict__ b_mlp_fg,
    const float* __restrict__ w_mlp_bg, const float* __restrict__ b_mlp_bg,
    const float* __restrict__ gfg_wih, const float* __restrict__ gfg_whh,
    const float* __restrict__ gfg_bih, const float* __restrict__ gfg_bhh,
    const float* __restrict__ gbg_wih, const float* __restrict__ gbg_whh,
    const float* __restrict__ gbg_bih, const float* __restrict__ gbg_bhh,
    const float* __restrict__ ln_rfg_g, const float* __restrict__ ln_rfg_b,
    const float* __restrict__ w_rfg, const float* __restrict__ b_rfg,
    const float* __restrict__ ln_rbg_g, const float* __restrict__ ln_rbg_b,
    const float* __restrict__ w_rbg, const float* __restrict__ b_rbg,
    const float* __restrict__ b_pos,
    const float* __restrict__ ln_fg_g, const float* __restrict__ ln_fg_b,
    float* __restrict__ ws)
{
  const int k = blockIdx.x, b = blockIdx.y, d = threadIdx.x;
  float* acc = ws + OFF_ACC + (size_t)b*ACC_STRIDE;
  __shared__ float xl[64], hl[64], rl[64];
  if (k < 4){
    const float invS = 1.0f/acc[A_S + 1 + k];
    const float pxv = ws[OFF_POS + b*8 + k*2 + 0];
    const float pyv = ws[OFF_POS + b*8 + k*2 + 1];
    const float wxc = (acc[A_WX + k] - pxv*acc[A_W0 + k])*invS;
    const float wyc = (acc[A_WY + k] - pyv*acc[A_W0 + k])*invS;
    xl[d] = acc[A_Y + k*64 + d]*invS*ln_fg_g[d]
          + wxc*ws[OFF_CXG + d] + wyc*ws[OFF_CYG + d] + ln_fg_b[d];
    const float h = ws[OFF_SFG + b*256 + k*64 + d];
    hl[d] = h;
    __syncthreads();
    const float upd = b_mlp_fg[d] + rowdot64(w_mlp_fg + d*64, xl);
    __syncthreads();
    xl[d] = upd;
    __syncthreads();
    const float gir = gfg_bih[d]     + rowdot64(gfg_wih + d*64, xl);
    const float giz = gfg_bih[64+d]  + rowdot64(gfg_wih + (64+d)*64, xl);
    const float gin = gfg_bih[128+d] + rowdot64(gfg_wih + (128+d)*64, xl);
    const float ghr = gfg_bhh[d]     + rowdot64(gfg_whh + d*64, hl);
    const float ghz = gfg_bhh[64+d]  + rowdot64(gfg_whh + (64+d)*64, hl);
    const float ghn = gfg_bhh[128+d] + rowdot64(gfg_whh + (128+d)*64, hl);
    const float r = 1.0f/(1.0f + expf(-(gir+ghr)));
    const float z = 1.0f/(1.0f + expf(-(giz+ghz)));
    const float nng = tanhf(fmaf(r, ghn, gin));
    const float hnew = (1.0f - z)*nng + z*h;
    const float m = wavesum(hnew)*(1.0f/64.0f);
    const float c = hnew - m;
    const float var = wavesum(c*c)*(1.0f/64.0f);
    const float rs = rsqrtf(var + LNEPS);
    rl[d] = c*rs*ln_rfg_g[d] + ln_rfg_b[d];
    __syncthreads();
    const float outv = hnew + b_rfg[d] + rowdot64(w_rfg + d*64, rl);
    ws[OFF_SFG + b*256 + k*64 + d] = outv;
    if (d < 2){
      const float P = acc[A_P + k*2 + d]*invS;
      const float T = acc[A_T + k*2 + d]*invS;
      float pn = P + tanhf(T + b_pos[d])*0.2f;
      pn = fminf(1.0f, fmaxf(-1.0f, pn));
      ws[OFF_POS + b*8 + k*2 + d] = pn;
    }
  } else {
    const float invS = 1.0f/acc[A_S];
    xl[d] = acc[A_YBG + d]*invS;
    const float h = ws[OFF_SBG + b*64 + d];
    hl[d] = h;
    __syncthreads();
    const float upd = b_mlp_bg[d] + rowdot64(w_mlp_bg + d*64, xl);
    __syncthreads();
    xl[d] = upd;
    __syncthreads();
    const float gir = gbg_bih[d]     + rowdot64(gbg_wih + d*64, xl);
    const float giz = gbg_bih[64+d]  + rowdot64(gbg_wih + (64+d)*64, xl);
    const float gin = gbg_bih[128+d] + rowdot64(gbg_wih + (128+d)*64, xl);
    const float ghr = gbg_bhh[d]     + rowdot64(gbg_whh + d*64, hl);
    const float ghz = gbg_bhh[64+d]  + rowdot64(gbg_whh + (64+d)*64, hl);
    const float ghn = gbg_bhh[128+d] + rowdot64(gbg_whh + (128+d)*64, hl);
    const float r = 1.0f/(1.0f + expf(-(gir+ghr)));
    const float z = 1.0f/(1.0f + expf(-(giz+ghz)));
    const float nng = tanhf(fmaf(r, ghn, gin));
    const float hnew = (1.0f - z)*nng + z*h;
    const float m = wavesum(hnew)*(1.0f/64.0f);
    const float c = hnew - m;
    const float var = wavesum(c*c)*(1.0f/64.0f);
    const float rs = rsqrtf(var + LNEPS);
    rl[d] = c*rs*ln_rbg_g[d] + ln_rbg_b[d];
    __syncthreads();
    const float outv = hnew + b_rbg[d] + rowdot64(w_rbg + d*64, rl);
    ws[OFF_SBG + b*64 + d] = outv;
  }
}

// ---- final output. grid (5,16) x 64 ----
__global__ __launch_bounds__(64) void k_final(
    const float* __restrict__ w_mlp_fg, const float* __restrict__ b_mlp_fg,
    const float* __restrict__ w_mlp_bg, const float* __restrict__ b_mlp_bg,
    const float* __restrict__ ln_fg_g, const float* __restrict__ ln_fg_b,
    const float* __restrict__ ws, float* __restrict__ out)
{
  const int k = blockIdx.x, b = blockIdx.y, d = threadIdx.x;
  const float* acc = ws + OFF_ACC + (size_t)b*ACC_STRIDE;
  __shared__ float xl[64];
  if (k < 4){
    const float invS = 1.0f/acc[A_S + 1 + k];
    const float pxv = ws[OFF_POS + b*8 + k*2 + 0];
    const float pyv = ws[OFF_POS + b*8 + k*2 + 1];
    const float wxc = (acc[A_WX + k] - pxv*acc[A_W0 + k])*invS;
    const float wyc = (acc[A_WY + k] - pyv*acc[A_W0 + k])*invS;
    xl[d] = acc[A_Y + k*64 + d]*invS*ln_fg_g[d]
          + wxc*ws[OFF_CXG + d] + wyc*ws[OFF_CYG + d] + ln_fg_b[d];
    __syncthreads();
    const float o = b_mlp_fg[d] + rowdot64(w_mlp_fg + d*64, xl);
    out[(size_t)(b*5 + 1 + k)*72 + d] = o;
    if (d < 8) out[(size_t)(b*5 + 1 + k)*72 + 64 + d] = acc[A_C + (k+1)*8 + d]*invS;
  } else {
    const float invS = 1.0f/acc[A_S];
    xl[d] = acc[A_YBG + d]*invS;
    __syncthreads();
    const float o = b_mlp_bg[d] + rowdot64(w_mlp_bg + d*64, xl);
    out[(size_t)(b*5)*72 + d] = o;
    if (d < 8) out[(size_t)(b*5)*72 + 64 + d] = acc[A_C + d]*invS;
  }
}

extern "C" void kernel_launch(void* const* d_in, const int* in_sizes, int n_in,
                              void* d_out, int out_size, void* d_ws, size_t ws_size,
                              hipStream_t stream)
{
  const float* feat          = (const float*)d_in[0];
  const float* feat_color    = (const float*)d_in[1];
  const float* w_grid        = (const float*)d_in[2];
  const float* b_grid        = (const float*)d_in[3];
  const float* w_kfg         = (const float*)d_in[4];
  const float* w_vfg         = (const float*)d_in[5];
  const float* w_kbg         = (const float*)d_in[6];
  const float* w_vbg         = (const float*)d_in[7];
  const float* ln_fg_g       = (const float*)d_in[8];
  const float* ln_fg_b       = (const float*)d_in[9];
  const float* w_mlp_fg      = (const float*)d_in[10];
  const float* b_mlp_fg      = (const float*)d_in[11];
  const float* ln_bg_g       = (const float*)d_in[12];
  const float* ln_bg_b       = (const float*)d_in[13];
  const float* w_mlp_bg      = (const float*)d_in[14];
  const float* b_mlp_bg      = (const float*)d_in[15];
  const float* slots_init_fg = (const float*)d_in[16];
  const float* slots_init_bg = (const float*)d_in[17];
  const float* fg_position   = (const float*)d_in[18];
  const float* w_pos         = (const float*)d_in[19];
  const float* b_pos         = (const float*)d_in[20];
  const float* ln_q_g        = (const float*)d_in[21];
  const float* ln_q_b        = (const float*)d_in[22];
  const float* w_q           = (const float*)d_in[23];
  const float* ln_qbg_g      = (const float*)d_in[24];
  const float* ln_qbg_b      = (const float*)d_in[25];
  const float* w_qbg         = (const float*)d_in[26];
  const float* gfg_wih       = (const float*)d_in[27];
  const float* gfg_whh       = (const float*)d_in[28];
  const float* gfg_bih       = (const float*)d_in[29];
  const float* gfg_bhh       = (const float*)d_in[30];
  const float* gbg_wih       = (const float*)d_in[31];
  const float* gbg_whh       = (const float*)d_in[32];
  const float* gbg_bih       = (const float*)d_in[33];
  const float* gbg_bhh       = (const float*)d_in[34];
  const float* ln_rfg_g      = (const float*)d_in[35];
  const float* ln_rfg_b      = (const float*)d_in[36];
  const float* w_rfg         = (const float*)d_in[37];
  const float* b_rfg         = (const float*)d_in[38];
  const float* ln_rbg_g      = (const float*)d_in[39];
  const float* ln_rbg_b      = (const float*)d_in[40];
  const float* w_rbg         = (const float*)d_in[41];
  const float* b_rbg         = (const float*)d_in[42];
  const float* ln_feat_g     = (const float*)d_in[43];
  const float* ln_feat_b     = (const float*)d_in[44];
  const float* ln_fc_g       = (const float*)d_in[45];
  const float* ln_fc_b       = (const float*)d_in[46];
  float* ws  = (float*)d_ws;
  float* out = (float*)d_out;

  hipLaunchKernelGGL(k_pre, dim3(2048), dim3(256), 0, stream,
                     feat, w_kfg, w_vfg, w_kbg, w_vbg, w_grid, b_grid,
                     ln_feat_g, ln_feat_b, ln_bg_g, ln_bg_b, ln_fg_g, ws);
  hipLaunchKernelGGL(k_init, dim3(16), dim3(256), 0, stream,
                     slots_init_fg, slots_init_bg, fg_position, w_grid, ln_fg_g, ws);
  for (int it = 0; it < NITER; ++it){
    hipLaunchKernelGGL(k_prep, dim3(5,16), dim3(64), 0, stream,
                       ln_q_g, ln_q_b, w_q, ln_qbg_g, ln_qbg_b, w_qbg,
                       w_mlp_fg, b_mlp_fg, w_mlp_bg, b_mlp_bg, ln_fg_b, ws);
    if (it < NITER-1){
      hipLaunchKernelGGL((k_main<0>), dim3(64,16), dim3(256), 0, stream,
                         feat_color, ln_fc_g, ln_fc_b, w_pos, ws);
      hipLaunchKernelGGL(k_update, dim3(5,16), dim3(64), 0, stream,
                         w_mlp_fg, b_mlp_fg, w_mlp_bg, b_mlp_bg,
                         gfg_wih, gfg_whh, gfg_bih, gfg_bhh,
                         gbg_wih, gbg_whh, gbg_bih, gbg_bhh,
                         ln_rfg_g, ln_rfg_b, w_rfg, b_rfg,
                         ln_rbg_g, ln_rbg_b, w_rbg, b_rbg,
                         b_pos, ln_fg_g, ln_fg_b, ws);
    } else {
      hipLaunchKernelGGL((k_main<1>), dim3(64,16), dim3(256), 0, stream,
                         feat_color, ln_fc_g, ln_fc_b, w_pos, ws);
      hipLaunchKernelGGL(k_final, dim3(5,16), dim3(64), 0, stream,
                         w_mlp_fg, b_mlp_fg, w_mlp_bg, b_mlp_bg,
                         ln_fg_g, ln_fg_b, ws, out);
    }
  }
}